// Round 1
// baseline (575.708 us; speedup 1.0000x reference)
//
#include <hip/hip_runtime.h>
#include <math.h>

#define B 4
#define L 512
#define H 512
#define NH 8
#define DK 64
#define RIN 53
#define RHID 32

__device__ __forceinline__ float waveReduceSum(float v) {
#pragma unroll
  for (int off = 32; off > 0; off >>= 1) v += __shfl_xor(v, off, 64);
  return v;
}
__device__ __forceinline__ float waveReduceMax(float v) {
#pragma unroll
  for (int off = 32; off > 0; off >>= 1) v = fmaxf(v, __shfl_xor(v, off, 64));
  return v;
}

// ---------------------------------------------------------------------------
// C[M,N] = A[M,K] @ W[K,N] + bias[N]   (f32, 64x64 tile, 256 thr, 4x4/thread)
// ---------------------------------------------------------------------------
#define GT 64
#define GBK 16
__global__ __launch_bounds__(256) void gemm_bias_kernel(
    const float* __restrict__ A, const float* __restrict__ W,
    const float* __restrict__ bias, float* __restrict__ C,
    int M, int N, int K) {
  __shared__ float sA[GBK][GT + 1];  // [kk][m]
  __shared__ float sB[GBK][GT + 1];  // [kk][n]
  const int n0 = blockIdx.x * GT;
  const int m0 = blockIdx.y * GT;
  const int tid = threadIdx.x;
  const int tn = tid & 15;   // 16 col groups
  const int tm = tid >> 4;   // 16 row groups
  float acc[4][4] = {};
  for (int k0 = 0; k0 < K; k0 += GBK) {
    {
      const int kk = tid & (GBK - 1);
      const int r = tid / GBK;  // 0..15
#pragma unroll
      for (int s = 0; s < 4; ++s) {
        const int row = r + s * 16;
        sA[kk][row] = A[(size_t)(m0 + row) * K + k0 + kk];
      }
    }
    {
      const int c = tid & 63;
      const int kb = tid >> 6;  // 0..3
#pragma unroll
      for (int s = 0; s < 4; ++s) {
        const int kk = kb + s * 4;
        sB[kk][c] = W[(size_t)(k0 + kk) * N + n0 + c];
      }
    }
    __syncthreads();
#pragma unroll
    for (int kk = 0; kk < GBK; ++kk) {
      float a[4], bb[4];
#pragma unroll
      for (int q = 0; q < 4; ++q) a[q] = sA[kk][tm * 4 + q];
#pragma unroll
      for (int q = 0; q < 4; ++q) bb[q] = sB[kk][tn * 4 + q];
#pragma unroll
      for (int q = 0; q < 4; ++q)
#pragma unroll
        for (int r = 0; r < 4; ++r) acc[q][r] = fmaf(a[q], bb[r], acc[q][r]);
    }
    __syncthreads();
  }
#pragma unroll
  for (int q = 0; q < 4; ++q) {
    const int row = m0 + tm * 4 + q;
#pragma unroll
    for (int r = 0; r < 4; ++r) {
      const int col = n0 + tn * 4 + r;
      C[(size_t)row * N + col] = acc[q][r] + bias[col];
    }
  }
}

// ---------------------------------------------------------------------------
// Fused pair-MLP + mask + softmax.  One block per (b, i) row.
// Each thread handles j = tid and j = tid+256.
// attn layout: (B, NH, L, L)
// ---------------------------------------------------------------------------
__global__ __launch_bounds__(256) void scores_softmax_kernel(
    const float* __restrict__ refCov, const int* __restrict__ mask,
    const float* __restrict__ W1, const float* __restrict__ b1,
    const float* __restrict__ W2, const float* __restrict__ b2,
    float* __restrict__ attn) {
  __shared__ float sW1[RIN * RHID];
  __shared__ float sb1[RHID];
  __shared__ float sW2[RHID * NH];
  __shared__ float sb2[NH];
  __shared__ float redbuf[4][NH];
  __shared__ int anyflag;
  const int tid = threadIdx.x;
  const int b = blockIdx.x >> 9;
  const int i = blockIdx.x & (L - 1);
  for (int t = tid; t < RIN * RHID; t += 256) sW1[t] = W1[t];
  for (int t = tid; t < RHID * NH; t += 256) sW2[t] = W2[t];
  if (tid < RHID) sb1[tid] = b1[tid];
  if (tid < NH) sb2[tid] = b2[tid];
  if (tid == 0) anyflag = 0;
  __syncthreads();

  const int mi = mask[b * L + i];
  float s[2][NH];
  int valid[2];
  int anylocal = 0;
#pragma unroll
  for (int p = 0; p < 2; ++p) {
    const int j = tid + p * 256;
    const float* rc = refCov + ((size_t)(b * L + i) * L + j) * RIN;
    float h1[RHID];
#pragma unroll
    for (int m = 0; m < RHID; ++m) h1[m] = sb1[m];
    for (int k = 0; k < RIN; ++k) {
      const float rk = rc[k];
#pragma unroll
      for (int m = 0; m < RHID; ++m) h1[m] = fmaf(rk, sW1[k * RHID + m], h1[m]);
    }
#pragma unroll
    for (int m = 0; m < RHID; ++m) h1[m] = fmaxf(h1[m], 0.f);
#pragma unroll
    for (int h = 0; h < NH; ++h) {
      float a = sb2[h];
#pragma unroll
      for (int m = 0; m < RHID; ++m) a = fmaf(h1[m], sW2[m * NH + h], a);
      s[p][h] = a;
    }
    const int mj = mask[b * L + j];
    valid[p] = (mi && mj);
    anylocal |= mj;
  }
  if (anylocal) anyflag = 1;  // benign same-value race

  const int wave = tid >> 6;
  const int lane = tid & 63;
  // per-head max over valid j
#pragma unroll
  for (int h = 0; h < NH; ++h) {
    float v = -INFINITY;
    if (valid[0]) v = s[0][h];
    if (valid[1]) v = fmaxf(v, s[1][h]);
    v = waveReduceMax(v);
    if (lane == 0) redbuf[wave][h] = v;
  }
  __syncthreads();
  float rmax[NH];
#pragma unroll
  for (int h = 0; h < NH; ++h)
    rmax[h] = fmaxf(fmaxf(redbuf[0][h], redbuf[1][h]),
                    fmaxf(redbuf[2][h], redbuf[3][h]));
  const int rowvalid = mi && anyflag;
  __syncthreads();  // before reusing redbuf

  float e[2][NH];
#pragma unroll
  for (int h = 0; h < NH; ++h) {
    e[0][h] = valid[0] ? __expf(s[0][h] - rmax[h]) : 0.f;
    e[1][h] = valid[1] ? __expf(s[1][h] - rmax[h]) : 0.f;
    float v = e[0][h] + e[1][h];
    v = waveReduceSum(v);
    if (lane == 0) redbuf[wave][h] = v;
  }
  __syncthreads();
  float rsum[NH];
#pragma unroll
  for (int h = 0; h < NH; ++h)
    rsum[h] = redbuf[0][h] + redbuf[1][h] + redbuf[2][h] + redbuf[3][h];

#pragma unroll
  for (int h = 0; h < NH; ++h) {
    const float inv = rowvalid ? (1.f / rsum[h]) : 0.f;
    const size_t base = ((size_t)(b * NH + h) * L + i) * L;
#pragma unroll
    for (int p = 0; p < 2; ++p) {
      const float o = rowvalid ? e[p][h] * inv : (1.0f / L);
      attn[base + tid + p * 256] = o;
    }
  }
}

// ---------------------------------------------------------------------------
// ctx[b, i, h*DK+dk] = sum_j attn[b,h,i,j] * value[b, j, h*DK+dk]
// block = (b, h, 16-row i tile), 256 threads
// ---------------------------------------------------------------------------
__global__ __launch_bounds__(256) void attn_value_kernel(
    const float* __restrict__ attn, const float* __restrict__ value,
    float* __restrict__ ctx) {
  const int bid = blockIdx.x;
  const int it = bid & 31;
  const int h = (bid >> 5) & 7;
  const int b = bid >> 8;
  const int i0 = it * 16;
  __shared__ float sV[64][64];
  __shared__ float sA[16][66];
  const int tid = threadIdx.x;
  const int dk = tid & 63;
  const int tq = tid >> 6;  // 0..3
  float acc[4] = {0.f, 0.f, 0.f, 0.f};
  for (int j0 = 0; j0 < L; j0 += 64) {
#pragma unroll
    for (int s = 0; s < 16; ++s) {
      const int jj = tq + s * 4;
      sV[jj][dk] = value[((size_t)(b * L) + j0 + jj) * H + h * DK + dk];
    }
#pragma unroll
    for (int s = 0; s < 4; ++s) {
      const int r = tq + s * 4;
      sA[r][dk] = attn[((size_t)(b * NH + h) * L + (i0 + r)) * L + j0 + dk];
    }
    __syncthreads();
#pragma unroll 8
    for (int jj = 0; jj < 64; ++jj) {
      const float v = sV[jj][dk];
#pragma unroll
      for (int q = 0; q < 4; ++q)
        acc[q] = fmaf(sA[tq * 4 + q][jj], v, acc[q]);
    }
    __syncthreads();
  }
#pragma unroll
  for (int q = 0; q < 4; ++q)
    ctx[((size_t)(b * L) + i0 + tq * 4 + q) * H + h * DK + dk] = acc[q];
}

// ---------------------------------------------------------------------------
// out = LN(x + proj) * gamma + beta   (block per row)
// ---------------------------------------------------------------------------
__global__ __launch_bounds__(256) void residual_ln_kernel(
    const float* __restrict__ x, const float* __restrict__ proj,
    const float* __restrict__ gamma, const float* __restrict__ beta,
    float* __restrict__ out) {
  const int row = blockIdx.x;
  const int tid = threadIdx.x;
  __shared__ float redS[4], redQ[4];
  float y[2];
  float ls = 0.f, lq = 0.f;
#pragma unroll
  for (int p = 0; p < 2; ++p) {
    const int c = tid + p * 256;
    const float v = x[(size_t)row * H + c] + proj[(size_t)row * H + c];
    y[p] = v;
    ls += v;
    lq += v * v;
  }
  const int lane = tid & 63, wave = tid >> 6;
  ls = waveReduceSum(ls);
  lq = waveReduceSum(lq);
  if (lane == 0) {
    redS[wave] = ls;
    redQ[wave] = lq;
  }
  __syncthreads();
  const float sum = redS[0] + redS[1] + redS[2] + redS[3];
  const float sq = redQ[0] + redQ[1] + redQ[2] + redQ[3];
  const float mu = sum * (1.f / H);
  const float var = sq * (1.f / H) - mu * mu;
  const float inv = rsqrtf(var + 1e-5f);
#pragma unroll
  for (int p = 0; p < 2; ++p) {
    const int c = tid + p * 256;
    out[(size_t)row * H + c] = (y[p] - mu) * inv * gamma[c] + beta[c];
  }
}

extern "C" void kernel_launch(void* const* d_in, const int* in_sizes, int n_in,
                              void* d_out, int out_size, void* d_ws,
                              size_t ws_size, hipStream_t stream) {
  const float* x = (const float*)d_in[0];
  const int* mask = (const int*)d_in[1];
  const float* refCov = (const float*)d_in[2];
  const float* Wv = (const float*)d_in[3];
  const float* bv = (const float*)d_in[4];
  const float* W1 = (const float*)d_in[5];
  const float* b1 = (const float*)d_in[6];
  const float* W2 = (const float*)d_in[7];
  const float* b2 = (const float*)d_in[8];
  const float* Wo = (const float*)d_in[9];
  const float* bo = (const float*)d_in[10];
  const float* gamma = (const float*)d_in[11];
  const float* beta = (const float*)d_in[12];
  float* out = (float*)d_out;

  // workspace layout (f32)
  const size_t n_attn = (size_t)B * NH * L * L;  // 8388608
  const size_t n_blh = (size_t)B * L * H;        // 1048576
  const size_t needed = (n_attn + 3 * n_blh) * sizeof(float);
  if (ws_size < needed) return;  // loud failure, avoids corruption
  float* attn = (float*)d_ws;
  float* value = attn + n_attn;
  float* ctx = value + n_blh;
  float* proj = ctx + n_blh;

  const int M = B * L;  // 2048
  dim3 gemmGrid(H / GT, M / GT);  // (8, 32)

  // 1. value = x @ Wv + bv
  gemm_bias_kernel<<<gemmGrid, 256, 0, stream>>>(x, Wv, bv, value, M, H, H);
  // 2. attn = softmax(mask(MLP(refCov)))
  scores_softmax_kernel<<<B * L, 256, 0, stream>>>(refCov, mask, W1, b1, W2,
                                                   b2, attn);
  // 3. ctx = attn @ value
  attn_value_kernel<<<B * NH * (L / 16), 256, 0, stream>>>(attn, value, ctx);
  // 4. proj = ctx @ Wo + bo
  gemm_bias_kernel<<<gemmGrid, 256, 0, stream>>>(ctx, Wo, bo, proj, M, H, H);
  // 5. out = LN(x + proj)
  residual_ln_kernel<<<M, 256, 0, stream>>>(x, proj, gamma, beta, out);
}

// Round 2
// 237.900 us; speedup vs baseline: 2.4200x; 2.4200x over previous
//
#include <hip/hip_runtime.h>
#include <math.h>

#define B 4
#define L 512
#define H 512
#define NH 8
#define DK 64
#define RIN 53
#define RHID 32

__device__ __forceinline__ float waveReduceSum(float v) {
#pragma unroll
  for (int off = 32; off > 0; off >>= 1) v += __shfl_xor(v, off, 64);
  return v;
}
__device__ __forceinline__ float waveReduceMax(float v) {
#pragma unroll
  for (int off = 32; off > 0; off >>= 1) v = fmaxf(v, __shfl_xor(v, off, 64));
  return v;
}

// ---------------------------------------------------------------------------
// C[M,N] = A[M,K] @ W[K,N] + bias[N]   (f32, 64x64 tile, 256 thr, 4x4/thread)
// ---------------------------------------------------------------------------
#define GT 64
#define GBK 16
__global__ __launch_bounds__(256) void gemm_bias_kernel(
    const float* __restrict__ A, const float* __restrict__ W,
    const float* __restrict__ bias, float* __restrict__ C,
    int M, int N, int K) {
  __shared__ float sA[GBK][GT + 1];  // [kk][m]
  __shared__ float sB[GBK][GT + 1];  // [kk][n]
  const int n0 = blockIdx.x * GT;
  const int m0 = blockIdx.y * GT;
  const int tid = threadIdx.x;
  const int tn = tid & 15;   // 16 col groups
  const int tm = tid >> 4;   // 16 row groups
  float acc[4][4] = {};
  for (int k0 = 0; k0 < K; k0 += GBK) {
    {
      const int kk = tid & (GBK - 1);
      const int r = tid / GBK;  // 0..15
#pragma unroll
      for (int s = 0; s < 4; ++s) {
        const int row = r + s * 16;
        sA[kk][row] = A[(size_t)(m0 + row) * K + k0 + kk];
      }
    }
    {
      const int c = tid & 63;
      const int kb = tid >> 6;  // 0..3
#pragma unroll
      for (int s = 0; s < 4; ++s) {
        const int kk = kb + s * 4;
        sB[kk][c] = W[(size_t)(k0 + kk) * N + n0 + c];
      }
    }
    __syncthreads();
#pragma unroll
    for (int kk = 0; kk < GBK; ++kk) {
      float a[4], bb[4];
#pragma unroll
      for (int q = 0; q < 4; ++q) a[q] = sA[kk][tm * 4 + q];
#pragma unroll
      for (int q = 0; q < 4; ++q) bb[q] = sB[kk][tn * 4 + q];
#pragma unroll
      for (int q = 0; q < 4; ++q)
#pragma unroll
        for (int r = 0; r < 4; ++r) acc[q][r] = fmaf(a[q], bb[r], acc[q][r]);
    }
    __syncthreads();
  }
#pragma unroll
  for (int q = 0; q < 4; ++q) {
    const int row = m0 + tm * 4 + q;
#pragma unroll
    for (int r = 0; r < 4; ++r) {
      const int col = n0 + tn * 4 + r;
      C[(size_t)row * N + col] = acc[q][r] + bias[col];
    }
  }
}

// ---------------------------------------------------------------------------
// Fused pair-MLP + mask + softmax, v2.
// One block per (b, i) row, 256 threads.
//  - early-exit for masked/empty rows (uniform 1/L)
//  - refCov staged through LDS in 2 chunks of 256 rows, coalesced float4 loads
//  - W1/W2/b1/b2 read via wave-uniform global loads (scalarized to s_load)
// attn layout: (B, NH, L, L)
// ---------------------------------------------------------------------------
__global__ __launch_bounds__(256) void scores_softmax_kernel(
    const float* __restrict__ refCov, const int* __restrict__ mask,
    const float* __restrict__ W1, const float* __restrict__ b1,
    const float* __restrict__ W2, const float* __restrict__ b2,
    float* __restrict__ attn) {
  __shared__ float sRC[256 * RIN];  // 54272 B
  __shared__ float redbuf[4][NH];
  __shared__ int s_any;
  const int tid = threadIdx.x;
  const int b = blockIdx.x >> 9;
  const int i = blockIdx.x & (L - 1);
  const int wave = tid >> 6;
  const int lane = tid & 63;

  const int mi = mask[b * L + i];
  const int m0 = mask[b * L + tid];        // mask of j = tid
  const int m1 = mask[b * L + 256 + tid];  // mask of j = tid + 256
  if (tid == 0) s_any = 0;
  __syncthreads();
  if (m0 | m1) s_any = 1;  // benign same-value race
  __syncthreads();

  if (mi == 0 || s_any == 0) {
    // fully-masked row: softmax of all-zeros -> uniform 1/L
    const float u = 1.0f / (float)L;
#pragma unroll
    for (int h = 0; h < NH; ++h) {
      const size_t base = ((size_t)(b * NH + h) * L + i) * L;
      attn[base + tid] = u;
      attn[base + tid + 256] = u;
    }
    return;
  }

  float s[2][NH];
#pragma unroll 1
  for (int c = 0; c < 2; ++c) {
    // stage 256 refCov rows (contiguous 54272 B) into LDS, coalesced
    {
      const float4* src =
          (const float4*)(refCov + ((size_t)(b * L + i) * L + c * 256) * RIN);
      float4* dst = (float4*)sRC;
      constexpr int NV4 = 256 * RIN / 4;  // 3392
#pragma unroll
      for (int q = 0; q < NV4 / 256 + 1; ++q) {
        const int idx = tid + q * 256;
        if (idx < NV4) dst[idx] = src[idx];
      }
    }
    __syncthreads();

    // per-thread MLP for j = c*256 + tid, rc row from LDS,
    // W1/b1/W2/b2 via uniform (scalar) loads
    const float* rc = &sRC[tid * RIN];
    float h1[RHID];
#pragma unroll
    for (int m = 0; m < RHID; ++m) h1[m] = b1[m];
    for (int k = 0; k < RIN; ++k) {
      const float rk = rc[k];
#pragma unroll
      for (int m = 0; m < RHID; ++m)
        h1[m] = fmaf(rk, W1[k * RHID + m], h1[m]);
    }
#pragma unroll
    for (int m = 0; m < RHID; ++m) h1[m] = fmaxf(h1[m], 0.f);
#pragma unroll
    for (int h = 0; h < NH; ++h) {
      float a = b2[h];
#pragma unroll
      for (int m = 0; m < RHID; ++m) a = fmaf(h1[m], W2[m * NH + h], a);
      s[c][h] = a;
    }
    __syncthreads();  // LDS reused by next chunk
  }

  // masked softmax over j (per head).  valid j: mask[j]!=0 (mi known 1).
#pragma unroll
  for (int h = 0; h < NH; ++h) {
    float v = -INFINITY;
    if (m0) v = s[0][h];
    if (m1) v = fmaxf(v, s[1][h]);
    v = waveReduceMax(v);
    if (lane == 0) redbuf[wave][h] = v;
  }
  __syncthreads();
  float rmax[NH];
#pragma unroll
  for (int h = 0; h < NH; ++h)
    rmax[h] = fmaxf(fmaxf(redbuf[0][h], redbuf[1][h]),
                    fmaxf(redbuf[2][h], redbuf[3][h]));
  __syncthreads();  // before reusing redbuf

  float e[2][NH];
#pragma unroll
  for (int h = 0; h < NH; ++h) {
    e[0][h] = m0 ? __expf(s[0][h] - rmax[h]) : 0.f;
    e[1][h] = m1 ? __expf(s[1][h] - rmax[h]) : 0.f;
    float v = e[0][h] + e[1][h];
    v = waveReduceSum(v);
    if (lane == 0) redbuf[wave][h] = v;
  }
  __syncthreads();
#pragma unroll
  for (int h = 0; h < NH; ++h) {
    const float inv =
        1.f / (redbuf[0][h] + redbuf[1][h] + redbuf[2][h] + redbuf[3][h]);
    const size_t base = ((size_t)(b * NH + h) * L + i) * L;
    attn[base + tid] = e[0][h] * inv;
    attn[base + tid + 256] = e[1][h] * inv;
  }
}

// ---------------------------------------------------------------------------
// ctx[b, i, h*DK+dk] = sum_j attn[b,h,i,j] * value[b, j, h*DK+dk]
// block = (b, h, 16-row i tile), 256 threads
// ---------------------------------------------------------------------------
__global__ __launch_bounds__(256) void attn_value_kernel(
    const float* __restrict__ attn, const float* __restrict__ value,
    float* __restrict__ ctx) {
  const int bid = blockIdx.x;
  const int it = bid & 31;
  const int h = (bid >> 5) & 7;
  const int b = bid >> 8;
  const int i0 = it * 16;
  __shared__ float sV[64][64];
  __shared__ float sA[16][66];
  const int tid = threadIdx.x;
  const int dk = tid & 63;
  const int tq = tid >> 6;  // 0..3
  float acc[4] = {0.f, 0.f, 0.f, 0.f};
  for (int j0 = 0; j0 < L; j0 += 64) {
#pragma unroll
    for (int s = 0; s < 16; ++s) {
      const int jj = tq + s * 4;
      sV[jj][dk] = value[((size_t)(b * L) + j0 + jj) * H + h * DK + dk];
    }
#pragma unroll
    for (int s = 0; s < 4; ++s) {
      const int r = tq + s * 4;
      sA[r][dk] = attn[((size_t)(b * NH + h) * L + (i0 + r)) * L + j0 + dk];
    }
    __syncthreads();
#pragma unroll 8
    for (int jj = 0; jj < 64; ++jj) {
      const float v = sV[jj][dk];
#pragma unroll
      for (int q = 0; q < 4; ++q)
        acc[q] = fmaf(sA[tq * 4 + q][jj], v, acc[q]);
    }
    __syncthreads();
  }
#pragma unroll
  for (int q = 0; q < 4; ++q)
    ctx[((size_t)(b * L) + i0 + tq * 4 + q) * H + h * DK + dk] = acc[q];
}

// ---------------------------------------------------------------------------
// out = LN(x + proj) * gamma + beta   (block per row)
// ---------------------------------------------------------------------------
__global__ __launch_bounds__(256) void residual_ln_kernel(
    const float* __restrict__ x, const float* __restrict__ proj,
    const float* __restrict__ gamma, const float* __restrict__ beta,
    float* __restrict__ out) {
  const int row = blockIdx.x;
  const int tid = threadIdx.x;
  __shared__ float redS[4], redQ[4];
  float y[2];
  float ls = 0.f, lq = 0.f;
#pragma unroll
  for (int p = 0; p < 2; ++p) {
    const int c = tid + p * 256;
    const float v = x[(size_t)row * H + c] + proj[(size_t)row * H + c];
    y[p] = v;
    ls += v;
    lq += v * v;
  }
  const int lane = tid & 63, wave = tid >> 6;
  ls = waveReduceSum(ls);
  lq = waveReduceSum(lq);
  if (lane == 0) {
    redS[wave] = ls;
    redQ[wave] = lq;
  }
  __syncthreads();
  const float sum = redS[0] + redS[1] + redS[2] + redS[3];
  const float sq = redQ[0] + redQ[1] + redQ[2] + redQ[3];
  const float mu = sum * (1.f / H);
  const float var = sq * (1.f / H) - mu * mu;
  const float inv = rsqrtf(var + 1e-5f);
#pragma unroll
  for (int p = 0; p < 2; ++p) {
    const int c = tid + p * 256;
    out[(size_t)row * H + c] = (y[p] - mu) * inv * gamma[c] + beta[c];
  }
}

extern "C" void kernel_launch(void* const* d_in, const int* in_sizes, int n_in,
                              void* d_out, int out_size, void* d_ws,
                              size_t ws_size, hipStream_t stream) {
  const float* x = (const float*)d_in[0];
  const int* mask = (const int*)d_in[1];
  const float* refCov = (const float*)d_in[2];
  const float* Wv = (const float*)d_in[3];
  const float* bv = (const float*)d_in[4];
  const float* W1 = (const float*)d_in[5];
  const float* b1 = (const float*)d_in[6];
  const float* W2 = (const float*)d_in[7];
  const float* b2 = (const float*)d_in[8];
  const float* Wo = (const float*)d_in[9];
  const float* bo = (const float*)d_in[10];
  const float* gamma = (const float*)d_in[11];
  const float* beta = (const float*)d_in[12];
  float* out = (float*)d_out;

  // workspace layout (f32)
  const size_t n_attn = (size_t)B * NH * L * L;  // 8388608
  const size_t n_blh = (size_t)B * L * H;        // 1048576
  const size_t needed = (n_attn + 3 * n_blh) * sizeof(float);
  if (ws_size < needed) return;  // loud failure, avoids corruption
  float* attn = (float*)d_ws;
  float* value = attn + n_attn;
  float* ctx = value + n_blh;
  float* proj = ctx + n_blh;

  const int M = B * L;  // 2048
  dim3 gemmGrid(H / GT, M / GT);  // (8, 32)

  // 1. value = x @ Wv + bv
  gemm_bias_kernel<<<gemmGrid, 256, 0, stream>>>(x, Wv, bv, value, M, H, H);
  // 2. attn = softmax(mask(MLP(refCov)))
  scores_softmax_kernel<<<B * L, 256, 0, stream>>>(refCov, mask, W1, b1, W2,
                                                   b2, attn);
  // 3. ctx = attn @ value
  attn_value_kernel<<<B * NH * (L / 16), 256, 0, stream>>>(attn, value, ctx);
  // 4. proj = ctx @ Wo + bo
  gemm_bias_kernel<<<gemmGrid, 256, 0, stream>>>(ctx, Wo, bo, proj, M, H, H);
  // 5. out = LN(x + proj)
  residual_ln_kernel<<<M, 256, 0, stream>>>(x, proj, gamma, beta, out);
}

// Round 3
// 209.252 us; speedup vs baseline: 2.7513x; 1.1369x over previous
//
#include <hip/hip_runtime.h>
#include <math.h>

#define B 4
#define L 512
#define H 512
#define NH 8
#define DK 64
#define RIN 53
#define RHID 32

__device__ __forceinline__ float waveReduceSum(float v) {
#pragma unroll
  for (int off = 32; off > 0; off >>= 1) v += __shfl_xor(v, off, 64);
  return v;
}
__device__ __forceinline__ float waveReduceMax(float v) {
#pragma unroll
  for (int off = 32; off > 0; off >>= 1) v = fmaxf(v, __shfl_xor(v, off, 64));
  return v;
}

__device__ __forceinline__ unsigned short f2bf(float f) {
  unsigned u = __float_as_uint(f);
  unsigned r = (u + 0x7fffu + ((u >> 16) & 1u)) >> 16;  // RNE
  return (unsigned short)r;
}

// ---------------------------------------------------------------------------
// C[M,N] = A[M,K] @ W[K,N] + bias[N]   (f32, 64x64 tile, 256 thr, 4x4/thread)
// ---------------------------------------------------------------------------
#define GT 64
#define GBK 16
__global__ __launch_bounds__(256) void gemm_bias_kernel(
    const float* __restrict__ A, const float* __restrict__ W,
    const float* __restrict__ bias, float* __restrict__ C,
    int M, int N, int K) {
  __shared__ float sA[GBK][GT + 1];  // [kk][m]
  __shared__ float sB[GBK][GT + 1];  // [kk][n]
  const int n0 = blockIdx.x * GT;
  const int m0 = blockIdx.y * GT;
  const int tid = threadIdx.x;
  const int tn = tid & 15;   // 16 col groups
  const int tm = tid >> 4;   // 16 row groups
  float acc[4][4] = {};
  for (int k0 = 0; k0 < K; k0 += GBK) {
    {
      const int kk = tid & (GBK - 1);
      const int r = tid / GBK;  // 0..15
#pragma unroll
      for (int s = 0; s < 4; ++s) {
        const int row = r + s * 16;
        sA[kk][row] = A[(size_t)(m0 + row) * K + k0 + kk];
      }
    }
    {
      const int c = tid & 63;
      const int kb = tid >> 6;  // 0..3
#pragma unroll
      for (int s = 0; s < 4; ++s) {
        const int kk = kb + s * 4;
        sB[kk][c] = W[(size_t)(k0 + kk) * N + n0 + c];
      }
    }
    __syncthreads();
#pragma unroll
    for (int kk = 0; kk < GBK; ++kk) {
      float a[4], bb[4];
#pragma unroll
      for (int q = 0; q < 4; ++q) a[q] = sA[kk][tm * 4 + q];
#pragma unroll
      for (int q = 0; q < 4; ++q) bb[q] = sB[kk][tn * 4 + q];
#pragma unroll
      for (int q = 0; q < 4; ++q)
#pragma unroll
        for (int r = 0; r < 4; ++r) acc[q][r] = fmaf(a[q], bb[r], acc[q][r]);
    }
    __syncthreads();
  }
#pragma unroll
  for (int q = 0; q < 4; ++q) {
    const int row = m0 + tm * 4 + q;
#pragma unroll
    for (int r = 0; r < 4; ++r) {
      const int col = n0 + tn * 4 + r;
      C[(size_t)row * N + col] = acc[q][r] + bias[col];
    }
  }
}

// ---------------------------------------------------------------------------
// Fused pair-MLP + mask + softmax, v3.
//  - refCov staged to LDS as bf16 (27.1 KB/block -> 5 blocks/CU, occ ~60%)
//  - chunk loop fully unrolled; all register arrays statically indexed
//  - W1/W2/b1/b2 via wave-uniform loads (scalarized to s_load, K$ resident)
//  - early-exit masked rows with float4 uniform writes
// attn layout: (B, NH, L, L)
// ---------------------------------------------------------------------------
__device__ __forceinline__ void pair_mlp(const unsigned short* sRC, int tid,
                                         const float* __restrict__ W1,
                                         const float* __restrict__ b1,
                                         const float* __restrict__ W2,
                                         const float* __restrict__ b2,
                                         float sc[NH]) {
  const unsigned short* rc = &sRC[tid * RIN];
  float h1[RHID];
#pragma unroll
  for (int m = 0; m < RHID; ++m) h1[m] = b1[m];
  for (int k = 0; k < RIN; ++k) {
    const float rk = __uint_as_float((unsigned)rc[k] << 16);
#pragma unroll
    for (int m = 0; m < RHID; ++m) h1[m] = fmaf(rk, W1[k * RHID + m], h1[m]);
  }
#pragma unroll
  for (int m = 0; m < RHID; ++m) h1[m] = fmaxf(h1[m], 0.f);
#pragma unroll
  for (int h = 0; h < NH; ++h) {
    float a = b2[h];
#pragma unroll
    for (int m = 0; m < RHID; ++m) a = fmaf(h1[m], W2[m * NH + h], a);
    sc[h] = a;
  }
}

__global__ __launch_bounds__(256) void scores_softmax_kernel(
    const float* __restrict__ refCov, const int* __restrict__ mask,
    const float* __restrict__ W1, const float* __restrict__ b1,
    const float* __restrict__ W2, const float* __restrict__ b2,
    float* __restrict__ attn) {
  __shared__ unsigned short sRC[256 * RIN];  // 27136 B (bf16)
  __shared__ float redbuf[4][NH];
  __shared__ int s_any;
  const int tid = threadIdx.x;
  const int b = blockIdx.x >> 9;
  const int i = blockIdx.x & (L - 1);
  const int wave = tid >> 6;
  const int lane = tid & 63;

  const int mi = mask[b * L + i];
  const int m0 = mask[b * L + tid];        // mask of j = tid
  const int m1 = mask[b * L + 256 + tid];  // mask of j = tid + 256
  if (tid == 0) s_any = 0;
  __syncthreads();
  if (m0 | m1) s_any = 1;  // benign same-value race
  __syncthreads();

  if (mi == 0 || s_any == 0) {
    // fully-masked row: softmax of all-zeros -> uniform 1/L
    const float u = 1.0f / (float)L;
    const float4 u4 = make_float4(u, u, u, u);
#pragma unroll
    for (int q = 0; q < 4; ++q) {
      const int f4 = q * 256 + tid;  // 0..1023  (NH*L/4 = 1024 float4)
      const int h = f4 >> 7;
      const int c4 = f4 & 127;
      float4* dst = (float4*)(attn + ((size_t)(b * NH + h) * L + i) * L) + c4;
      *dst = u4;
    }
    return;
  }

  constexpr int NV4 = 256 * RIN / 4;  // 3392 float4 per chunk
  float sc0[NH], sc1[NH];

  // ---- chunk 0: j in [0,256) ----
  {
    const float4* src =
        (const float4*)(refCov + ((size_t)(b * L + i) * L + 0) * RIN);
#pragma unroll
    for (int q = 0; q < (NV4 + 255) / 256; ++q) {
      const int idx = tid + q * 256;
      if (idx < NV4) {
        const float4 v = src[idx];
        ushort4 u;
        u.x = f2bf(v.x);
        u.y = f2bf(v.y);
        u.z = f2bf(v.z);
        u.w = f2bf(v.w);
        *(ushort4*)(&sRC[idx * 4]) = u;
      }
    }
    __syncthreads();
    pair_mlp(sRC, tid, W1, b1, W2, b2, sc0);
    __syncthreads();  // before restaging
  }
  // ---- chunk 1: j in [256,512) ----
  {
    const float4* src =
        (const float4*)(refCov + ((size_t)(b * L + i) * L + 256) * RIN);
#pragma unroll
    for (int q = 0; q < (NV4 + 255) / 256; ++q) {
      const int idx = tid + q * 256;
      if (idx < NV4) {
        const float4 v = src[idx];
        ushort4 u;
        u.x = f2bf(v.x);
        u.y = f2bf(v.y);
        u.z = f2bf(v.z);
        u.w = f2bf(v.w);
        *(ushort4*)(&sRC[idx * 4]) = u;
      }
    }
    __syncthreads();
    pair_mlp(sRC, tid, W1, b1, W2, b2, sc1);
  }

  // masked softmax over j (per head).  valid j: mask[j]!=0 (mi known 1).
#pragma unroll
  for (int h = 0; h < NH; ++h) {
    float v = -INFINITY;
    if (m0) v = sc0[h];
    if (m1) v = fmaxf(v, sc1[h]);
    v = waveReduceMax(v);
    if (lane == 0) redbuf[wave][h] = v;
  }
  __syncthreads();
  float rmax[NH];
#pragma unroll
  for (int h = 0; h < NH; ++h)
    rmax[h] = fmaxf(fmaxf(redbuf[0][h], redbuf[1][h]),
                    fmaxf(redbuf[2][h], redbuf[3][h]));
  __syncthreads();  // before reusing redbuf

  float e0[NH], e1[NH];
#pragma unroll
  for (int h = 0; h < NH; ++h) {
    e0[h] = m0 ? __expf(sc0[h] - rmax[h]) : 0.f;
    e1[h] = m1 ? __expf(sc1[h] - rmax[h]) : 0.f;
    float v = e0[h] + e1[h];
    v = waveReduceSum(v);
    if (lane == 0) redbuf[wave][h] = v;
  }
  __syncthreads();
#pragma unroll
  for (int h = 0; h < NH; ++h) {
    const float inv =
        1.f / (redbuf[0][h] + redbuf[1][h] + redbuf[2][h] + redbuf[3][h]);
    const size_t base = ((size_t)(b * NH + h) * L + i) * L;
    attn[base + tid] = e0[h] * inv;
    attn[base + tid + 256] = e1[h] * inv;
  }
}

// ---------------------------------------------------------------------------
// ctx[b, i, h*DK+dk] = sum_j attn[b,h,i,j] * value[b, j, h*DK+dk]
// block = (b, h, 16-row i tile), 256 threads
// ---------------------------------------------------------------------------
__global__ __launch_bounds__(256) void attn_value_kernel(
    const float* __restrict__ attn, const float* __restrict__ value,
    float* __restrict__ ctx) {
  const int bid = blockIdx.x;
  const int it = bid & 31;
  const int h = (bid >> 5) & 7;
  const int b = bid >> 8;
  const int i0 = it * 16;
  __shared__ float sV[64][64];
  __shared__ float sA[16][66];
  const int tid = threadIdx.x;
  const int dk = tid & 63;
  const int tq = tid >> 6;  // 0..3
  float acc[4] = {0.f, 0.f, 0.f, 0.f};
  for (int j0 = 0; j0 < L; j0 += 64) {
#pragma unroll
    for (int s = 0; s < 16; ++s) {
      const int jj = tq + s * 4;
      sV[jj][dk] = value[((size_t)(b * L) + j0 + jj) * H + h * DK + dk];
    }
#pragma unroll
    for (int s = 0; s < 4; ++s) {
      const int r = tq + s * 4;
      sA[r][dk] = attn[((size_t)(b * NH + h) * L + (i0 + r)) * L + j0 + dk];
    }
    __syncthreads();
#pragma unroll 8
    for (int jj = 0; jj < 64; ++jj) {
      const float v = sV[jj][dk];
#pragma unroll
      for (int q = 0; q < 4; ++q)
        acc[q] = fmaf(sA[tq * 4 + q][jj], v, acc[q]);
    }
    __syncthreads();
  }
#pragma unroll
  for (int q = 0; q < 4; ++q)
    ctx[((size_t)(b * L) + i0 + tq * 4 + q) * H + h * DK + dk] = acc[q];
}

// ---------------------------------------------------------------------------
// out = LN(x + proj) * gamma + beta   (block per row)
// ---------------------------------------------------------------------------
__global__ __launch_bounds__(256) void residual_ln_kernel(
    const float* __restrict__ x, const float* __restrict__ proj,
    const float* __restrict__ gamma, const float* __restrict__ beta,
    float* __restrict__ out) {
  const int row = blockIdx.x;
  const int tid = threadIdx.x;
  __shared__ float redS[4], redQ[4];
  float y[2];
  float ls = 0.f, lq = 0.f;
#pragma unroll
  for (int p = 0; p < 2; ++p) {
    const int c = tid + p * 256;
    const float v = x[(size_t)row * H + c] + proj[(size_t)row * H + c];
    y[p] = v;
    ls += v;
    lq += v * v;
  }
  const int lane = tid & 63, wave = tid >> 6;
  ls = waveReduceSum(ls);
  lq = waveReduceSum(lq);
  if (lane == 0) {
    redS[wave] = ls;
    redQ[wave] = lq;
  }
  __syncthreads();
  const float sum = redS[0] + redS[1] + redS[2] + redS[3];
  const float sq = redQ[0] + redQ[1] + redQ[2] + redQ[3];
  const float mu = sum * (1.f / H);
  const float var = sq * (1.f / H) - mu * mu;
  const float inv = rsqrtf(var + 1e-5f);
#pragma unroll
  for (int p = 0; p < 2; ++p) {
    const int c = tid + p * 256;
    out[(size_t)row * H + c] = (y[p] - mu) * inv * gamma[c] + beta[c];
  }
}

extern "C" void kernel_launch(void* const* d_in, const int* in_sizes, int n_in,
                              void* d_out, int out_size, void* d_ws,
                              size_t ws_size, hipStream_t stream) {
  const float* x = (const float*)d_in[0];
  const int* mask = (const int*)d_in[1];
  const float* refCov = (const float*)d_in[2];
  const float* Wv = (const float*)d_in[3];
  const float* bv = (const float*)d_in[4];
  const float* W1 = (const float*)d_in[5];
  const float* b1 = (const float*)d_in[6];
  const float* W2 = (const float*)d_in[7];
  const float* b2 = (const float*)d_in[8];
  const float* Wo = (const float*)d_in[9];
  const float* bo = (const float*)d_in[10];
  const float* gamma = (const float*)d_in[11];
  const float* beta = (const float*)d_in[12];
  float* out = (float*)d_out;

  // workspace layout (f32)
  const size_t n_attn = (size_t)B * NH * L * L;  // 8388608
  const size_t n_blh = (size_t)B * L * H;        // 1048576
  const size_t needed = (n_attn + 3 * n_blh) * sizeof(float);
  if (ws_size < needed) return;  // loud failure, avoids corruption
  float* attn = (float*)d_ws;
  float* value = attn + n_attn;
  float* ctx = value + n_blh;
  float* proj = ctx + n_blh;

  const int M = B * L;  // 2048
  dim3 gemmGrid(H / GT, M / GT);  // (8, 32)

  // 1. value = x @ Wv + bv
  gemm_bias_kernel<<<gemmGrid, 256, 0, stream>>>(x, Wv, bv, value, M, H, H);
  // 2. attn = softmax(mask(MLP(refCov)))
  scores_softmax_kernel<<<B * L, 256, 0, stream>>>(refCov, mask, W1, b1, W2,
                                                   b2, attn);
  // 3. ctx = attn @ value
  attn_value_kernel<<<B * NH * (L / 16), 256, 0, stream>>>(attn, value, ctx);
  // 4. proj = ctx @ Wo + bo
  gemm_bias_kernel<<<gemmGrid, 256, 0, stream>>>(ctx, Wo, bo, proj, M, H, H);
  // 5. out = LN(x + proj)
  residual_ln_kernel<<<M, 256, 0, stream>>>(x, proj, gamma, beta, out);
}

// Round 4
// 172.065 us; speedup vs baseline: 3.3459x; 1.2161x over previous
//
#include <hip/hip_runtime.h>
#include <math.h>

#define B 4
#define L 512
#define H 512
#define NH 8
#define DK 64
#define RIN 53
#define RHID 32

using short8 = __attribute__((ext_vector_type(8))) short;
using f32x4 = __attribute__((ext_vector_type(4))) float;

__device__ __forceinline__ float waveReduceSum(float v) {
#pragma unroll
  for (int off = 32; off > 0; off >>= 1) v += __shfl_xor(v, off, 64);
  return v;
}

__device__ __forceinline__ unsigned short f2bf(float f) {
  unsigned u = __float_as_uint(f);
  unsigned r = (u + 0x7fffu + ((u >> 16) & 1u)) >> 16;  // RNE
  return (unsigned short)r;
}

// ---------------------------------------------------------------------------
// C[M,N] = A[M,K] @ W[K,N] + bias[N]   (f32, 64x64 tile, 256 thr, 4x4/thread)
// ---------------------------------------------------------------------------
#define GT 64
#define GBK 16
__global__ __launch_bounds__(256) void gemm_bias_kernel(
    const float* __restrict__ A, const float* __restrict__ W,
    const float* __restrict__ bias, float* __restrict__ C,
    int M, int N, int K) {
  __shared__ float sA[GBK][GT + 1];  // [kk][m]
  __shared__ float sB[GBK][GT + 1];  // [kk][n]
  const int n0 = blockIdx.x * GT;
  const int m0 = blockIdx.y * GT;
  const int tid = threadIdx.x;
  const int tn = tid & 15;   // 16 col groups
  const int tm = tid >> 4;   // 16 row groups
  float acc[4][4] = {};
  for (int k0 = 0; k0 < K; k0 += GBK) {
    {
      const int kk = tid & (GBK - 1);
      const int r = tid / GBK;  // 0..15
#pragma unroll
      for (int s = 0; s < 4; ++s) {
        const int row = r + s * 16;
        sA[kk][row] = A[(size_t)(m0 + row) * K + k0 + kk];
      }
    }
    {
      const int c = tid & 63;
      const int kb = tid >> 6;  // 0..3
#pragma unroll
      for (int s = 0; s < 4; ++s) {
        const int kk = kb + s * 4;
        sB[kk][c] = W[(size_t)(k0 + kk) * N + n0 + c];
      }
    }
    __syncthreads();
#pragma unroll
    for (int kk = 0; kk < GBK; ++kk) {
      float a[4], bb[4];
#pragma unroll
      for (int q = 0; q < 4; ++q) a[q] = sA[kk][tm * 4 + q];
#pragma unroll
      for (int q = 0; q < 4; ++q) bb[q] = sB[kk][tn * 4 + q];
#pragma unroll
      for (int q = 0; q < 4; ++q)
#pragma unroll
        for (int r = 0; r < 4; ++r) acc[q][r] = fmaf(a[q], bb[r], acc[q][r]);
    }
    __syncthreads();
  }
#pragma unroll
  for (int q = 0; q < 4; ++q) {
    const int row = m0 + tm * 4 + q;
#pragma unroll
    for (int r = 0; r < 4; ++r) {
      const int col = n0 + tn * 4 + r;
      C[(size_t)row * N + col] = acc[q][r] + bias[col];
    }
  }
}

// ---------------------------------------------------------------------------
// Fused pair-MLP + mask + softmax, v4: MFMA for both MLP layers.
// Block = (b, i), 256 threads = 4 waves; wave w owns rows [w*64, w*64+64)
// of each 256-row chunk (2 chunks).
//  layer1: h1 = relu(RC @ W1 + b1)   via mfma 16x16x32 bf16 (K 53->64 pad)
//  layer2: S  = h1 @ W2 + b2        via mfma (N 8->16 pad)
//  W1/W2 fragments in VGPRs, loaded once per block (no per-k scalar loads).
// attn layout: (B, NH, L, L)
// ---------------------------------------------------------------------------
__global__ __launch_bounds__(256) void scores_softmax_kernel(
    const float* __restrict__ refCov, const int* __restrict__ mask,
    const float* __restrict__ W1, const float* __restrict__ b1,
    const float* __restrict__ W2, const float* __restrict__ b2,
    float* __restrict__ attn) {
  __shared__ unsigned short sRC[256 * RIN + 16];  // bf16, linear [row*53+k]
  __shared__ unsigned short sH1[256 * 33];        // h1 bf16, stride 33
  __shared__ unsigned short sMask[2 * 256];
  __shared__ float redbuf[4][16];
  __shared__ int s_any;

  const int tid = threadIdx.x;
  const int b = blockIdx.x >> 9;
  const int i = blockIdx.x & (L - 1);
  const int w = tid >> 6;   // wave
  const int l = tid & 63;   // lane
  const int g = l >> 4;     // quarter-wave group (0..3)
  const int a = l & 15;     // low 4 bits: A-row / B-col / C-col

  const int mi = mask[b * L + i];
  const int m0 = mask[b * L + tid];
  const int m1 = mask[b * L + 256 + tid];
  if (tid == 0) s_any = 0;
  __syncthreads();
  if (m0 | m1) s_any = 1;  // benign same-value race
  sMask[tid] = (unsigned short)(m0 != 0);
  sMask[tid + 256] = (unsigned short)(m1 != 0);
  __syncthreads();

  if (mi == 0 || s_any == 0) {
    // fully-masked row: softmax of all-zeros -> uniform 1/L
    const float u = 1.0f / (float)L;
    const float4 u4 = make_float4(u, u, u, u);
#pragma unroll
    for (int q = 0; q < 4; ++q) {
      const int f4 = q * 256 + tid;  // NH*L/4 = 1024 float4
      const int h = f4 >> 7;
      const int c4 = f4 & 127;
      float4* dst = (float4*)(attn + ((size_t)(b * NH + h) * L + i) * L) + c4;
      *dst = u4;
    }
    return;
  }

  // ---- per-block weight fragments (k-position convention: k = g*8+e,
  //      consistently used for A and B of each layer) ----
  short8 w1f[2][2];  // [kstep][ntile]
#pragma unroll
  for (int ks = 0; ks < 2; ++ks)
#pragma unroll
    for (int nt = 0; nt < 2; ++nt)
#pragma unroll
      for (int e = 0; e < 8; ++e) {
        const int k = ks * 32 + g * 8 + e;
        w1f[ks][nt][e] =
            (k < RIN) ? (short)f2bf(W1[k * RHID + nt * 16 + a]) : (short)0;
      }
  short8 w2f;
#pragma unroll
  for (int e = 0; e < 8; ++e) {
    const int k = g * 8 + e;  // k < 32 always
    w2f[e] = (a < NH) ? (short)f2bf(W2[k * NH + a]) : (short)0;
  }
  const float b1v0 = b1[a];
  const float b1v1 = b1[16 + a];
  const float b2v = (a < NH) ? b2[a] : 0.f;

  constexpr int NV4 = 256 * RIN / 4;  // 3392 float4 per chunk
  f32x4 sc[2][4];                     // [chunk][mtile]
  unsigned vbits[2];

#pragma unroll
  for (int c = 0; c < 2; ++c) {
    if (c) __syncthreads();  // protect sRC before restaging
    // ---- stage 256 rows of refCov as bf16 into LDS (coalesced) ----
    {
      const float4* src =
          (const float4*)(refCov + ((size_t)(b * L + i) * L + c * 256) * RIN);
#pragma unroll
      for (int q = 0; q < (NV4 + 255) / 256; ++q) {
        const int idx = tid + q * 256;
        if (idx < NV4) {
          const float4 v = src[idx];
          ushort4 u;
          u.x = f2bf(v.x);
          u.y = f2bf(v.y);
          u.z = f2bf(v.z);
          u.w = f2bf(v.w);
          *(ushort4*)(&sRC[idx * 4]) = u;
        }
      }
    }
    __syncthreads();

    // ---- layer 1: h1 = relu(RC @ W1 + b1), 16 MFMA ----
    f32x4 h1acc[4][2];
#pragma unroll
    for (int mt = 0; mt < 4; ++mt) {
      h1acc[mt][0] = f32x4{b1v0, b1v0, b1v0, b1v0};
      h1acc[mt][1] = f32x4{b1v1, b1v1, b1v1, b1v1};
    }
#pragma unroll
    for (int mt = 0; mt < 4; ++mt) {
      const int row = w * 64 + mt * 16 + a;
#pragma unroll
      for (int ks = 0; ks < 2; ++ks) {
        short8 af;
#pragma unroll
        for (int e = 0; e < 8; ++e) {
          const int k = ks * 32 + g * 8 + e;
          af[e] = (k < RIN) ? (short)sRC[row * RIN + k] : (short)0;
        }
#pragma unroll
        for (int nt = 0; nt < 2; ++nt)
          h1acc[mt][nt] = __builtin_amdgcn_mfma_f32_16x16x32_bf16(
              af, w1f[ks][nt], h1acc[mt][nt], 0, 0, 0);
      }
    }

    // ---- relu + wave-local transpose of h1 through LDS ----
#pragma unroll
    for (int mt = 0; mt < 4; ++mt)
#pragma unroll
      for (int nt = 0; nt < 2; ++nt)
#pragma unroll
        for (int r = 0; r < 4; ++r) {
          const float v = fmaxf(h1acc[mt][nt][r], 0.f);
          const int row = w * 64 + mt * 16 + g * 4 + r;  // C row
          const int col = nt * 16 + a;                   // C col
          sH1[row * 33 + col] = f2bf(v);
        }
    // wave-local rows: producer == consumer wave, lgkmcnt ordering suffices

    // ---- layer 2: S = h1 @ W2 + b2, 4 MFMA ----
#pragma unroll
    for (int mt = 0; mt < 4; ++mt) {
      const int row = w * 64 + mt * 16 + a;
      short8 af2;
#pragma unroll
      for (int e = 0; e < 8; ++e) af2[e] = (short)sH1[row * 33 + g * 8 + e];
      f32x4 acc = f32x4{b2v, b2v, b2v, b2v};
      acc = __builtin_amdgcn_mfma_f32_16x16x32_bf16(af2, w2f, acc, 0, 0, 0);
      sc[c][mt] = acc;
    }

    // ---- validity bits for this chunk ----
    unsigned vb = 0;
#pragma unroll
    for (int mt = 0; mt < 4; ++mt)
#pragma unroll
      for (int r = 0; r < 4; ++r) {
        const int j = c * 256 + w * 64 + mt * 16 + g * 4 + r;
        if (sMask[j]) vb |= 1u << (mt * 4 + r);
      }
    vbits[c] = vb;
  }

  // ---- masked softmax over j for head h = a (lanes a<8 are real heads) ----
  float mx = -INFINITY;
#pragma unroll
  for (int c = 0; c < 2; ++c)
#pragma unroll
    for (int mt = 0; mt < 4; ++mt)
#pragma unroll
      for (int r = 0; r < 4; ++r)
        if ((vbits[c] >> (mt * 4 + r)) & 1u) mx = fmaxf(mx, sc[c][mt][r]);
  mx = fmaxf(mx, __shfl_xor(mx, 16, 64));
  mx = fmaxf(mx, __shfl_xor(mx, 32, 64));
  if (g == 0) redbuf[w][a] = mx;
  __syncthreads();
  const float rmax = fmaxf(fmaxf(redbuf[0][a], redbuf[1][a]),
                           fmaxf(redbuf[2][a], redbuf[3][a]));
  __syncthreads();  // before reusing redbuf

  float lsum = 0.f;
#pragma unroll
  for (int c = 0; c < 2; ++c)
#pragma unroll
    for (int mt = 0; mt < 4; ++mt)
#pragma unroll
      for (int r = 0; r < 4; ++r) {
        const int valid = (vbits[c] >> (mt * 4 + r)) & 1u;
        const float e = valid ? __expf(sc[c][mt][r] - rmax) : 0.f;
        sc[c][mt][r] = e;
        lsum += e;
      }
  lsum += __shfl_xor(lsum, 16, 64);
  lsum += __shfl_xor(lsum, 32, 64);
  if (g == 0) redbuf[w][a] = lsum;
  __syncthreads();
  const float rsum =
      redbuf[0][a] + redbuf[1][a] + redbuf[2][a] + redbuf[3][a];
  const float inv = 1.f / rsum;

  if (a < NH) {
#pragma unroll
    for (int c = 0; c < 2; ++c)
#pragma unroll
      for (int mt = 0; mt < 4; ++mt) {
        float4 o;
        o.x = sc[c][mt][0] * inv;
        o.y = sc[c][mt][1] * inv;
        o.z = sc[c][mt][2] * inv;
        o.w = sc[c][mt][3] * inv;
        float4* dst = (float4*)(attn + ((size_t)(b * NH + a) * L + i) * L +
                                c * 256 + w * 64 + mt * 16 + g * 4);
        *dst = o;
      }
  }
}

// ---------------------------------------------------------------------------
// ctx[b, i, h*DK+dk] = sum_j attn[b,h,i,j] * value[b, j, h*DK+dk]
// block = (b, h, 16-row i tile), 256 threads
// ---------------------------------------------------------------------------
__global__ __launch_bounds__(256) void attn_value_kernel(
    const float* __restrict__ attn, const float* __restrict__ value,
    float* __restrict__ ctx) {
  const int bid = blockIdx.x;
  const int it = bid & 31;
  const int h = (bid >> 5) & 7;
  const int b = bid >> 8;
  const int i0 = it * 16;
  __shared__ float sV[64][64];
  __shared__ float sA[16][66];
  const int tid = threadIdx.x;
  const int dk = tid & 63;
  const int tq = tid >> 6;  // 0..3
  float acc[4] = {0.f, 0.f, 0.f, 0.f};
  for (int j0 = 0; j0 < L; j0 += 64) {
#pragma unroll
    for (int s = 0; s < 16; ++s) {
      const int jj = tq + s * 4;
      sV[jj][dk] = value[((size_t)(b * L) + j0 + jj) * H + h * DK + dk];
    }
#pragma unroll
    for (int s = 0; s < 4; ++s) {
      const int r = tq + s * 4;
      sA[r][dk] = attn[((size_t)(b * NH + h) * L + (i0 + r)) * L + j0 + dk];
    }
    __syncthreads();
#pragma unroll 8
    for (int jj = 0; jj < 64; ++jj) {
      const float v = sV[jj][dk];
#pragma unroll
      for (int q = 0; q < 4; ++q)
        acc[q] = fmaf(sA[tq * 4 + q][jj], v, acc[q]);
    }
    __syncthreads();
  }
#pragma unroll
  for (int q = 0; q < 4; ++q)
    ctx[((size_t)(b * L) + i0 + tq * 4 + q) * H + h * DK + dk] = acc[q];
}

// ---------------------------------------------------------------------------
// out = LN(x + proj) * gamma + beta   (block per row)
// ---------------------------------------------------------------------------
__global__ __launch_bounds__(256) void residual_ln_kernel(
    const float* __restrict__ x, const float* __restrict__ proj,
    const float* __restrict__ gamma, const float* __restrict__ beta,
    float* __restrict__ out) {
  const int row = blockIdx.x;
  const int tid = threadIdx.x;
  __shared__ float redS[4], redQ[4];
  float y[2];
  float ls = 0.f, lq = 0.f;
#pragma unroll
  for (int p = 0; p < 2; ++p) {
    const int c = tid + p * 256;
    const float v = x[(size_t)row * H + c] + proj[(size_t)row * H + c];
    y[p] = v;
    ls += v;
    lq += v * v;
  }
  const int lane = tid & 63, wave = tid >> 6;
  ls = waveReduceSum(ls);
  lq = waveReduceSum(lq);
  if (lane == 0) {
    redS[wave] = ls;
    redQ[wave] = lq;
  }
  __syncthreads();
  const float sum = redS[0] + redS[1] + redS[2] + redS[3];
  const float sq = redQ[0] + redQ[1] + redQ[2] + redQ[3];
  const float mu = sum * (1.f / H);
  const float var = sq * (1.f / H) - mu * mu;
  const float inv = rsqrtf(var + 1e-5f);
#pragma unroll
  for (int p = 0; p < 2; ++p) {
    const int c = tid + p * 256;
    out[(size_t)row * H + c] = (y[p] - mu) * inv * gamma[c] + beta[c];
  }
}

extern "C" void kernel_launch(void* const* d_in, const int* in_sizes, int n_in,
                              void* d_out, int out_size, void* d_ws,
                              size_t ws_size, hipStream_t stream) {
  const float* x = (const float*)d_in[0];
  const int* mask = (const int*)d_in[1];
  const float* refCov = (const float*)d_in[2];
  const float* Wv = (const float*)d_in[3];
  const float* bv = (const float*)d_in[4];
  const float* W1 = (const float*)d_in[5];
  const float* b1 = (const float*)d_in[6];
  const float* W2 = (const float*)d_in[7];
  const float* b2 = (const float*)d_in[8];
  const float* Wo = (const float*)d_in[9];
  const float* bo = (const float*)d_in[10];
  const float* gamma = (const float*)d_in[11];
  const float* beta = (const float*)d_in[12];
  float* out = (float*)d_out;

  // workspace layout (f32)
  const size_t n_attn = (size_t)B * NH * L * L;  // 8388608
  const size_t n_blh = (size_t)B * L * H;        // 1048576
  const size_t needed = (n_attn + 3 * n_blh) * sizeof(float);
  if (ws_size < needed) return;  // loud failure, avoids corruption
  float* attn = (float*)d_ws;
  float* value = attn + n_attn;
  float* ctx = value + n_blh;
  float* proj = ctx + n_blh;

  const int M = B * L;  // 2048
  dim3 gemmGrid(H / GT, M / GT);  // (8, 32)

  // 1. value = x @ Wv + bv
  gemm_bias_kernel<<<gemmGrid, 256, 0, stream>>>(x, Wv, bv, value, M, H, H);
  // 2. attn = softmax(mask(MLP(refCov)))
  scores_softmax_kernel<<<B * L, 256, 0, stream>>>(refCov, mask, W1, b1, W2,
                                                   b2, attn);
  // 3. ctx = attn @ value
  attn_value_kernel<<<B * NH * (L / 16), 256, 0, stream>>>(attn, value, ctx);
  // 4. proj = ctx @ Wo + bo
  gemm_bias_kernel<<<gemmGrid, 256, 0, stream>>>(ctx, Wo, bo, proj, M, H, H);
  // 5. out = LN(x + proj)
  residual_ln_kernel<<<M, 256, 0, stream>>>(x, proj, gamma, beta, out);
}

// Round 5
// 120.055 us; speedup vs baseline: 4.7954x; 1.4332x over previous
//
#include <hip/hip_runtime.h>
#include <math.h>

#define B 4
#define L 512
#define H 512
#define NH 8
#define DK 64
#define RIN 53
#define RHID 32

using short8 = __attribute__((ext_vector_type(8))) short;
using ushort8v = __attribute__((ext_vector_type(8))) unsigned short;
using f32x4 = __attribute__((ext_vector_type(4))) float;

__device__ __forceinline__ float waveReduceSum(float v) {
#pragma unroll
  for (int off = 32; off > 0; off >>= 1) v += __shfl_xor(v, off, 64);
  return v;
}

__device__ __forceinline__ unsigned short f2bf(float f) {
  unsigned u = __float_as_uint(f);
  unsigned r = (u + 0x7fffu + ((u >> 16) & 1u)) >> 16;  // RNE
  return (unsigned short)r;
}

// ---------------------------------------------------------------------------
// prep: f32 -> bf16 cast (n4 float4s)
// ---------------------------------------------------------------------------
__global__ __launch_bounds__(256) void cast_bf16_kernel(
    const float* __restrict__ src, unsigned short* __restrict__ dst, int n4) {
  const int idx = blockIdx.x * 256 + threadIdx.x;
  if (idx < n4) {
    const float4 v = ((const float4*)src)[idx];
    ushort4 o;
    o.x = f2bf(v.x);
    o.y = f2bf(v.y);
    o.z = f2bf(v.z);
    o.w = f2bf(v.w);
    ((ushort4*)dst)[idx] = o;
  }
}

// ---------------------------------------------------------------------------
// prep: W[512][512] f32 -> WT[512][512] bf16 with WT[n][k] = W[k][n]
// grid (8,8), 64x64 tiles via LDS
// ---------------------------------------------------------------------------
__global__ __launch_bounds__(256) void transpose_w_kernel(
    const float* __restrict__ W, unsigned short* __restrict__ WT) {
  __shared__ float sT[64][65];
  const int k0 = blockIdx.x * 64, n0 = blockIdx.y * 64;
  const int tid = threadIdx.x;
  {
    const int r = tid >> 2, c0 = (tid & 3) * 16;
#pragma unroll
    for (int cc = 0; cc < 16; cc += 4) {
      const float4 v = *(const float4*)(W + (size_t)(k0 + r) * 512 + n0 + c0 + cc);
      sT[r][c0 + cc] = v.x;
      sT[r][c0 + cc + 1] = v.y;
      sT[r][c0 + cc + 2] = v.z;
      sT[r][c0 + cc + 3] = v.w;
    }
  }
  __syncthreads();
  {
    const int n = tid >> 2, c0 = (tid & 3) * 16;
    ushort8v o0, o1;
#pragma unroll
    for (int cc = 0; cc < 8; ++cc) o0[cc] = f2bf(sT[c0 + cc][n]);
#pragma unroll
    for (int cc = 0; cc < 8; ++cc) o1[cc] = f2bf(sT[c0 + 8 + cc][n]);
    *(ushort8v*)(WT + (size_t)(n0 + n) * 512 + k0 + c0) = o0;
    *(ushort8v*)(WT + (size_t)(n0 + n) * 512 + k0 + c0 + 8) = o1;
  }
}

// ---------------------------------------------------------------------------
// bf16 MFMA GEMM core: C[32 x 64] tile, K=512, 256 threads (4 waves, 2x2
// quadrants of 16x32).  A[m][k] bf16 lda; B either [n][k] (pre-transposed)
// or [k][n] (TRANS_B staging).  Register prefetch of next K-chunk.
// ---------------------------------------------------------------------------
template <bool OUT_BF16, bool TRANS_B>
__device__ __forceinline__ void gemm32x64(
    const unsigned short* __restrict__ A, int lda,
    const unsigned short* __restrict__ Bs, int ldb,
    const float* __restrict__ bias, void* __restrict__ Cp, int ldc) {
  __shared__ unsigned short sA[32 * 40];
  __shared__ unsigned short sB[64 * 40];
  __shared__ float sC[32][68];
  const int tid = threadIdx.x;
  const int w = tid >> 6, l = tid & 63, g = l >> 4, a = l & 15;
  const int wm = (w >> 1) * 16, wn = (w & 1) * 32;
  f32x4 acc0 = {}, acc1 = {};
  ushort8v aReg, bReg;

  // prefetch chunk 0
  if (tid < 128)
    aReg = *(const ushort8v*)(A + (size_t)(tid >> 2) * lda + (tid & 3) * 8);
  if constexpr (!TRANS_B) {
    bReg = *(const ushort8v*)(Bs + (size_t)(tid >> 2) * ldb + (tid & 3) * 8);
  } else {
    const int d = tid & 63, j8 = tid >> 6;
#pragma unroll
    for (int e = 0; e < 8; ++e) bReg[e] = Bs[(size_t)(j8 * 8 + e) * ldb + d];
  }

  for (int k0 = 0; k0 < 512; k0 += 32) {
    if (tid < 128) *(ushort8v*)(&sA[(tid >> 2) * 40 + (tid & 3) * 8]) = aReg;
    if constexpr (!TRANS_B)
      *(ushort8v*)(&sB[(tid >> 2) * 40 + (tid & 3) * 8]) = bReg;
    else
      *(ushort8v*)(&sB[(tid & 63) * 40 + (tid >> 6) * 8]) = bReg;
    __syncthreads();
    // prefetch next chunk while computing
    if (k0 < 480) {
      const int kn = k0 + 32;
      if (tid < 128)
        aReg = *(const ushort8v*)(A + (size_t)(tid >> 2) * lda + kn + (tid & 3) * 8);
      if constexpr (!TRANS_B) {
        bReg = *(const ushort8v*)(Bs + (size_t)(tid >> 2) * ldb + kn + (tid & 3) * 8);
      } else {
        const int d = tid & 63, j8 = tid >> 6;
#pragma unroll
        for (int e = 0; e < 8; ++e)
          bReg[e] = Bs[(size_t)(kn + j8 * 8 + e) * ldb + d];
      }
    }
    const short8 af = *(const short8*)(&sA[(wm + a) * 40 + g * 8]);
    const short8 bf0 = *(const short8*)(&sB[(wn + a) * 40 + g * 8]);
    const short8 bf1 = *(const short8*)(&sB[(wn + 16 + a) * 40 + g * 8]);
    acc0 = __builtin_amdgcn_mfma_f32_16x16x32_bf16(af, bf0, acc0, 0, 0, 0);
    acc1 = __builtin_amdgcn_mfma_f32_16x16x32_bf16(af, bf1, acc1, 0, 0, 0);
    __syncthreads();
  }

  // C fragments -> LDS (row = wm + g*4 + r, col = wn + nt*16 + a)
#pragma unroll
  for (int r = 0; r < 4; ++r) {
    sC[wm + g * 4 + r][wn + a] = acc0[r];
    sC[wm + g * 4 + r][wn + 16 + a] = acc1[r];
  }
  __syncthreads();
  // coalesced write-out: thread t: row m = t>>3, cols (t&7)*8 .. +8
  {
    const int m = tid >> 3, c8 = (tid & 7) * 8;
    float v[8];
#pragma unroll
    for (int cc = 0; cc < 8; ++cc) {
      v[cc] = sC[m][c8 + cc];
      if (bias) v[cc] += bias[c8 + cc];
    }
    if constexpr (OUT_BF16) {
      ushort8v o;
#pragma unroll
      for (int cc = 0; cc < 8; ++cc) o[cc] = f2bf(v[cc]);
      *(ushort8v*)((unsigned short*)Cp + (size_t)m * ldc + c8) = o;
    } else {
      float4 o0 = make_float4(v[0], v[1], v[2], v[3]);
      float4 o1 = make_float4(v[4], v[5], v[6], v[7]);
      *(float4*)((float*)Cp + (size_t)m * ldc + c8) = o0;
      *(float4*)((float*)Cp + (size_t)m * ldc + c8 + 4) = o1;
    }
  }
}

// value = xb @ WvT + bv  (bf16 out), grid (8, 64)
__global__ __launch_bounds__(256) void gemm_xw_kernel(
    const unsigned short* __restrict__ Ab, const unsigned short* __restrict__ BT,
    const float* __restrict__ bias, unsigned short* __restrict__ C) {
  const int n0 = blockIdx.x * 64;
  const int m0 = blockIdx.y * 32;
  gemm32x64<true, false>(Ab + (size_t)m0 * 512, 512, BT + (size_t)n0 * 512, 512,
                         bias + n0, C + (size_t)m0 * 512 + n0, 512);
}

// proj = ctx @ WoT + bo  (f32 out), grid (8, 64)
__global__ __launch_bounds__(256) void gemm_proj_kernel(
    const unsigned short* __restrict__ Ab, const unsigned short* __restrict__ BT,
    const float* __restrict__ bias, float* __restrict__ C) {
  const int n0 = blockIdx.x * 64;
  const int m0 = blockIdx.y * 32;
  gemm32x64<false, false>(Ab + (size_t)m0 * 512, 512, BT + (size_t)n0 * 512, 512,
                          bias + n0, C + (size_t)m0 * 512 + n0, 512);
}

// ctx[b,i,h*64+d] = sum_j attn[b,h,i,j] * value[b,j,h*64+d], grid 512
__global__ __launch_bounds__(256) void attn_value_kernel(
    const unsigned short* __restrict__ attnb,
    const unsigned short* __restrict__ val, unsigned short* __restrict__ ctx) {
  const int bid = blockIdx.x;  // it(16) x h(8) x b(4)
  const int it = bid & 15, h = (bid >> 4) & 7, b = bid >> 7;
  const int i0 = it * 32;
  gemm32x64<true, true>(attnb + ((size_t)((b * 8 + h) * 512 + i0)) * 512, 512,
                        val + (size_t)b * 512 * 512 + h * 64, 512, nullptr,
                        ctx + ((size_t)(b * 512 + i0)) * 512 + h * 64, 512);
}

// ---------------------------------------------------------------------------
// Fused pair-MLP + mask + softmax, v5: b128-friendly LDS layouts, bf16 out.
// Block = (b, i), 256 threads = 4 waves; wave w owns rows [w*64, w*64+64)
// of each 256-row chunk (2 chunks).
// ---------------------------------------------------------------------------
__global__ __launch_bounds__(256) void scores_softmax_kernel(
    const float* __restrict__ refCov, const int* __restrict__ mask,
    const float* __restrict__ W1, const float* __restrict__ b1,
    const float* __restrict__ W2, const float* __restrict__ b2,
    unsigned short* __restrict__ attnb) {
  __shared__ unsigned short sRC[256 * 56];  // 28672 B, rows padded to 56
  __shared__ unsigned short sH1[256 * 34];  // 17408 B
  __shared__ unsigned short sZero[8];
  __shared__ unsigned short sMask[2 * 256];
  __shared__ float redbuf[4][16];
  __shared__ int s_any;

  const int tid = threadIdx.x;
  const int b = blockIdx.x >> 9;
  const int i = blockIdx.x & (L - 1);
  const int w = tid >> 6;
  const int l = tid & 63;
  const int g = l >> 4;
  const int a = l & 15;

  const int mi = mask[b * L + i];
  const int m0 = mask[b * L + tid];
  const int m1 = mask[b * L + 256 + tid];
  if (tid == 0) s_any = 0;
  __syncthreads();
  if (m0 | m1) s_any = 1;  // benign same-value race
  sMask[tid] = (unsigned short)(m0 != 0);
  sMask[tid + 256] = (unsigned short)(m1 != 0);
  // zero-fill pad cols 53..55 (row = tid) and the broadcast zero line
  sRC[tid * 56 + 53] = 0;
  sRC[tid * 56 + 54] = 0;
  sRC[tid * 56 + 55] = 0;
  if (tid < 8) sZero[tid] = 0;
  __syncthreads();

  if (mi == 0 || s_any == 0) {
    // fully-masked row: uniform 1/L (= 2^-9, exact in bf16)
    const ushort4 u4 = {0x3B00u, 0x3B00u, 0x3B00u, 0x3B00u};
#pragma unroll
    for (int q = 0; q < 4; ++q) {
      const int f4 = q * 256 + tid;  // 1024 ushort4 = NH*L shorts
      const int h = f4 >> 7;
      const int c4 = f4 & 127;
      *(ushort4*)(attnb + ((size_t)(b * NH + h) * L + i) * L + c4 * 4) = u4;
    }
    return;
  }

  // ---- per-block weight fragments (k = ks*32 + g*8 + e) ----
  short8 w1f[2][2];  // [kstep][ntile]
#pragma unroll
  for (int ks = 0; ks < 2; ++ks)
#pragma unroll
    for (int nt = 0; nt < 2; ++nt)
#pragma unroll
      for (int e = 0; e < 8; ++e) {
        const int k = ks * 32 + g * 8 + e;
        w1f[ks][nt][e] =
            (k < RIN) ? (short)f2bf(W1[k * RHID + nt * 16 + a]) : (short)0;
      }
  short8 w2f;
#pragma unroll
  for (int e = 0; e < 8; ++e) {
    const int k = g * 8 + e;
    w2f[e] = (a < NH) ? (short)f2bf(W2[k * NH + a]) : (short)0;
  }
  const float b1v0 = b1[a];
  const float b1v1 = b1[16 + a];
  const float b2v = (a < NH) ? b2[a] : 0.f;

  constexpr int NV4 = 256 * RIN / 4;  // 3392 float4 per chunk
  f32x4 sc[2][4];
  unsigned vbits[2];

#pragma unroll 1
  for (int c = 0; c < 2; ++c) {
    if (c) __syncthreads();  // protect sRC before restaging
    // ---- stage 256 rows as bf16 into padded LDS (coalesced reads) ----
    {
      const float4* src =
          (const float4*)(refCov + ((size_t)(b * L + i) * L + c * 256) * RIN);
#pragma unroll
      for (int q = 0; q < 14; ++q) {
        const int idx = tid + q * 256;
        if (idx < NV4) {
          const float4 v = src[idx];
          const int p = idx * 4;
          const int row = p / RIN;
          const int col = p - row * RIN;
          float vv[4] = {v.x, v.y, v.z, v.w};
#pragma unroll
          for (int s = 0; s < 4; ++s) {
            int c2 = col + s, r2 = row;
            if (c2 >= RIN) {
              c2 -= RIN;
              r2 += 1;
            }
            sRC[r2 * 56 + c2] = f2bf(vv[s]);
          }
        }
      }
    }
    __syncthreads();

    // ---- layer 1: h1 = relu(RC @ W1 + b1), 16 MFMA / wave ----
    f32x4 h1acc[4][2];
#pragma unroll
    for (int mt = 0; mt < 4; ++mt) {
      h1acc[mt][0] = f32x4{b1v0, b1v0, b1v0, b1v0};
      h1acc[mt][1] = f32x4{b1v1, b1v1, b1v1, b1v1};
    }
#pragma unroll
    for (int mt = 0; mt < 4; ++mt) {
      const int row = w * 64 + mt * 16 + a;
#pragma unroll
      for (int ks = 0; ks < 2; ++ks) {
        const int k8 = ks * 4 + g;
        const unsigned short* srcp =
            (k8 < 7) ? &sRC[row * 56 + k8 * 8] : &sZero[0];
        const short8 af = *(const short8*)srcp;
#pragma unroll
        for (int nt = 0; nt < 2; ++nt)
          h1acc[mt][nt] = __builtin_amdgcn_mfma_f32_16x16x32_bf16(
              af, w1f[ks][nt], h1acc[mt][nt], 0, 0, 0);
      }
    }

    // ---- relu + wave-local transpose of h1 through LDS ----
#pragma unroll
    for (int mt = 0; mt < 4; ++mt)
#pragma unroll
      for (int nt = 0; nt < 2; ++nt)
#pragma unroll
        for (int r = 0; r < 4; ++r) {
          const float v = fmaxf(h1acc[mt][nt][r], 0.f);
          const int row = w * 64 + mt * 16 + g * 4 + r;
          const int col = nt * 16 + a;
          sH1[row * 34 + col] = f2bf(v);
        }

    // ---- layer 2: S = h1 @ W2 + b2, 4 MFMA / wave ----
#pragma unroll
    for (int mt = 0; mt < 4; ++mt) {
      const int row = w * 64 + mt * 16 + a;
      const short8 af2 = *(const short8*)(&sH1[row * 34 + g * 8]);
      f32x4 acc = f32x4{b2v, b2v, b2v, b2v};
      acc = __builtin_amdgcn_mfma_f32_16x16x32_bf16(af2, w2f, acc, 0, 0, 0);
      sc[c][mt] = acc;
    }

    // ---- validity bits ----
    unsigned vb = 0;
#pragma unroll
    for (int mt = 0; mt < 4; ++mt)
#pragma unroll
      for (int r = 0; r < 4; ++r) {
        const int j = c * 256 + w * 64 + mt * 16 + g * 4 + r;
        if (sMask[j]) vb |= 1u << (mt * 4 + r);
      }
    vbits[c] = vb;
  }

  // ---- masked softmax over j for head h = a (lanes a<8 real) ----
  float mx = -INFINITY;
#pragma unroll
  for (int c = 0; c < 2; ++c)
#pragma unroll
    for (int mt = 0; mt < 4; ++mt)
#pragma unroll
      for (int r = 0; r < 4; ++r)
        if ((vbits[c] >> (mt * 4 + r)) & 1u) mx = fmaxf(mx, sc[c][mt][r]);
  mx = fmaxf(mx, __shfl_xor(mx, 16, 64));
  mx = fmaxf(mx, __shfl_xor(mx, 32, 64));
  if (g == 0) redbuf[w][a] = mx;
  __syncthreads();
  const float rmax = fmaxf(fmaxf(redbuf[0][a], redbuf[1][a]),
                           fmaxf(redbuf[2][a], redbuf[3][a]));
  __syncthreads();

  float lsum = 0.f;
#pragma unroll
  for (int c = 0; c < 2; ++c)
#pragma unroll
    for (int mt = 0; mt < 4; ++mt)
#pragma unroll
      for (int r = 0; r < 4; ++r) {
        const int valid = (vbits[c] >> (mt * 4 + r)) & 1u;
        const float e = valid ? __expf(sc[c][mt][r] - rmax) : 0.f;
        sc[c][mt][r] = e;
        lsum += e;
      }
  lsum += __shfl_xor(lsum, 16, 64);
  lsum += __shfl_xor(lsum, 32, 64);
  if (g == 0) redbuf[w][a] = lsum;
  __syncthreads();
  const float rsum = redbuf[0][a] + redbuf[1][a] + redbuf[2][a] + redbuf[3][a];
  const float inv = 1.f / rsum;

  if (a < NH) {
#pragma unroll
    for (int c = 0; c < 2; ++c)
#pragma unroll
      for (int mt = 0; mt < 4; ++mt) {
        ushort4 o;
        o.x = f2bf(sc[c][mt][0] * inv);
        o.y = f2bf(sc[c][mt][1] * inv);
        o.z = f2bf(sc[c][mt][2] * inv);
        o.w = f2bf(sc[c][mt][3] * inv);
        *(ushort4*)(attnb + ((size_t)(b * NH + a) * L + i) * L + c * 256 +
                    w * 64 + mt * 16 + g * 4) = o;
      }
  }
}

// ---------------------------------------------------------------------------
// out = LN(x + proj) * gamma + beta   (block per row)
// ---------------------------------------------------------------------------
__global__ __launch_bounds__(256) void residual_ln_kernel(
    const float* __restrict__ x, const float* __restrict__ proj,
    const float* __restrict__ gamma, const float* __restrict__ beta,
    float* __restrict__ out) {
  const int row = blockIdx.x;
  const int tid = threadIdx.x;
  __shared__ float redS[4], redQ[4];
  float y[2];
  float ls = 0.f, lq = 0.f;
#pragma unroll
  for (int p = 0; p < 2; ++p) {
    const int c = tid + p * 256;
    const float v = x[(size_t)row * H + c] + proj[(size_t)row * H + c];
    y[p] = v;
    ls += v;
    lq += v * v;
  }
  const int lane = tid & 63, wave = tid >> 6;
  ls = waveReduceSum(ls);
  lq = waveReduceSum(lq);
  if (lane == 0) {
    redS[wave] = ls;
    redQ[wave] = lq;
  }
  __syncthreads();
  const float sum = redS[0] + redS[1] + redS[2] + redS[3];
  const float sq = redQ[0] + redQ[1] + redQ[2] + redQ[3];
  const float mu = sum * (1.f / H);
  const float var = sq * (1.f / H) - mu * mu;
  const float inv = rsqrtf(var + 1e-5f);
#pragma unroll
  for (int p = 0; p < 2; ++p) {
    const int c = tid + p * 256;
    out[(size_t)row * H + c] = (y[p] - mu) * inv * gamma[c] + beta[c];
  }
}

extern "C" void kernel_launch(void* const* d_in, const int* in_sizes, int n_in,
                              void* d_out, int out_size, void* d_ws,
                              size_t ws_size, hipStream_t stream) {
  const float* x = (const float*)d_in[0];
  const int* mask = (const int*)d_in[1];
  const float* refCov = (const float*)d_in[2];
  const float* Wv = (const float*)d_in[3];
  const float* bv = (const float*)d_in[4];
  const float* W1 = (const float*)d_in[5];
  const float* b1 = (const float*)d_in[6];
  const float* W2 = (const float*)d_in[7];
  const float* b2 = (const float*)d_in[8];
  const float* Wo = (const float*)d_in[9];
  const float* bo = (const float*)d_in[10];
  const float* gamma = (const float*)d_in[11];
  const float* beta = (const float*)d_in[12];
  float* out = (float*)d_out;

  // workspace layout
  const size_t n_attn = (size_t)B * NH * L * L;  // 8388608 (bf16)
  const size_t n_blh = (size_t)B * L * H;        // 1048576
  const size_t n_w = (size_t)H * H;              // 262144
  unsigned short* attnb = (unsigned short*)d_ws;
  unsigned short* xb = attnb + n_attn;
  unsigned short* value_b = xb + n_blh;
  unsigned short* ctx = value_b + n_blh;
  unsigned short* WvT = ctx + n_blh;
  unsigned short* WoT = WvT + n_w;
  float* proj = (float*)(WoT + n_w);
  const size_t needed = (n_attn + 3 * n_blh + 2 * n_w) * 2 + n_blh * 4;
  if (ws_size < needed) return;

  const int M = B * L;  // 2048

  // prep: casts/transposes
  cast_bf16_kernel<<<(n_blh / 4 + 255) / 256, 256, 0, stream>>>(x, xb,
                                                                n_blh / 4);
  transpose_w_kernel<<<dim3(8, 8), 256, 0, stream>>>(Wv, WvT);
  transpose_w_kernel<<<dim3(8, 8), 256, 0, stream>>>(Wo, WoT);
  // 1. value = xb @ WvT + bv  (bf16)
  gemm_xw_kernel<<<dim3(8, M / 32), 256, 0, stream>>>(xb, WvT, bv, value_b);
  // 2. attn = softmax(mask(MLP(refCov)))  (bf16)
  scores_softmax_kernel<<<B * L, 256, 0, stream>>>(refCov, mask, W1, b1, W2,
                                                   b2, attnb);
  // 3. ctx = attn @ value  (bf16)
  attn_value_kernel<<<512, 256, 0, stream>>>(attnb, value_b, ctx);
  // 4. proj = ctx @ WoT + bo  (f32)
  gemm_proj_kernel<<<dim3(8, M / 32), 256, 0, stream>>>(ctx, WoT, bo, proj);
  // 5. out = LN(x + proj)
  residual_ln_kernel<<<M, 256, 0, stream>>>(x, proj, gamma, beta, out);
}

// Round 6
// 84.791 us; speedup vs baseline: 6.7897x; 1.4159x over previous
//
#include <hip/hip_runtime.h>
#include <math.h>

#define B 4
#define L 512
#define H 512
#define NH 8
#define DK 64
#define RIN 53
#define RHID 32

using short8 = __attribute__((ext_vector_type(8))) short;
using ushort8v = __attribute__((ext_vector_type(8))) unsigned short;
using f32x4 = __attribute__((ext_vector_type(4))) float;

__device__ __forceinline__ float waveReduceSum(float v) {
#pragma unroll
  for (int off = 32; off > 0; off >>= 1) v += __shfl_xor(v, off, 64);
  return v;
}

__device__ __forceinline__ unsigned short f2bf(float f) {
  unsigned u = __float_as_uint(f);
  unsigned r = (u + 0x7fffu + ((u >> 16) & 1u)) >> 16;  // RNE
  return (unsigned short)r;
}

// ---------------------------------------------------------------------------
// prep: Wv and Wo [k][n] f32 -> WT[n][k] bf16, one launch, grid (8,8,2)
// ---------------------------------------------------------------------------
__global__ __launch_bounds__(256) void transpose_w2_kernel(
    const float* __restrict__ Wv, const float* __restrict__ Wo,
    unsigned short* __restrict__ WvT, unsigned short* __restrict__ WoT) {
  const float* W = blockIdx.z ? Wo : Wv;
  unsigned short* WT = blockIdx.z ? WoT : WvT;
  __shared__ float sT[64][65];
  const int k0 = blockIdx.x * 64, n0 = blockIdx.y * 64;
  const int tid = threadIdx.x;
  {
    const int r = tid >> 2, c0 = (tid & 3) * 16;
#pragma unroll
    for (int cc = 0; cc < 16; cc += 4) {
      const float4 v =
          *(const float4*)(W + (size_t)(k0 + r) * 512 + n0 + c0 + cc);
      sT[r][c0 + cc] = v.x;
      sT[r][c0 + cc + 1] = v.y;
      sT[r][c0 + cc + 2] = v.z;
      sT[r][c0 + cc + 3] = v.w;
    }
  }
  __syncthreads();
  {
    const int n = tid >> 2, c0 = (tid & 3) * 16;
    ushort8v o0, o1;
#pragma unroll
    for (int cc = 0; cc < 8; ++cc) o0[cc] = f2bf(sT[c0 + cc][n]);
#pragma unroll
    for (int cc = 0; cc < 8; ++cc) o1[cc] = f2bf(sT[c0 + 8 + cc][n]);
    *(ushort8v*)(WT + (size_t)(n0 + n) * 512 + k0 + c0) = o0;
    *(ushort8v*)(WT + (size_t)(n0 + n) * 512 + k0 + c0 + 8) = o1;
  }
}

// ---------------------------------------------------------------------------
// bf16 MFMA GEMM core: C[32 m x 64 n], K=512, 256 thr (4 waves, 2x2 quads).
// A: [m][k] bf16 (AMODE 0) or f32 converted on stage (AMODE 1).
// B: [n][k] bf16 (pre-transposed), coalesced ushort8 loads.
// OMODE: 0 = f32 store, 1 = bf16 store, 2 = bf16 TRANSPOSED store (C^T).
// ---------------------------------------------------------------------------
template <int AMODE, int OMODE>
__device__ __forceinline__ void gemm32x64(
    const void* __restrict__ Aq, int lda, const unsigned short* __restrict__ Bs,
    int ldb, const float* __restrict__ bias, void* __restrict__ Cp, int ldc) {
  __shared__ unsigned short sA[32 * 40];
  __shared__ unsigned short sB[64 * 40];
  __shared__ float sC[32][68];
  const int tid = threadIdx.x;
  const int w = tid >> 6, l = tid & 63, g = l >> 4, a = l & 15;
  const int wm = (w >> 1) * 16, wn = (w & 1) * 32;
  f32x4 acc0 = {}, acc1 = {};
  ushort8v aReg{}, bReg;

  auto loadA = [&](int k0) {
    ushort8v r{};
    if (tid < 128) {
      if constexpr (AMODE == 1) {
        const float* Af = (const float*)Aq;
        const float* p = Af + (size_t)(tid >> 2) * lda + k0 + (tid & 3) * 8;
        const float4 v0 = *(const float4*)p;
        const float4 v1 = *(const float4*)(p + 4);
        r[0] = f2bf(v0.x); r[1] = f2bf(v0.y); r[2] = f2bf(v0.z); r[3] = f2bf(v0.w);
        r[4] = f2bf(v1.x); r[5] = f2bf(v1.y); r[6] = f2bf(v1.z); r[7] = f2bf(v1.w);
      } else {
        const unsigned short* Ab = (const unsigned short*)Aq;
        r = *(const ushort8v*)(Ab + (size_t)(tid >> 2) * lda + k0 + (tid & 3) * 8);
      }
    }
    return r;
  };
  auto loadB = [&](int k0) {
    return *(const ushort8v*)(Bs + (size_t)(tid >> 2) * ldb + k0 + (tid & 3) * 8);
  };

  aReg = loadA(0);
  bReg = loadB(0);
  for (int k0 = 0; k0 < 512; k0 += 32) {
    if (tid < 128) *(ushort8v*)(&sA[(tid >> 2) * 40 + (tid & 3) * 8]) = aReg;
    *(ushort8v*)(&sB[(tid >> 2) * 40 + (tid & 3) * 8]) = bReg;
    __syncthreads();
    if (k0 < 480) {
      aReg = loadA(k0 + 32);
      bReg = loadB(k0 + 32);
    }
    const short8 af = *(const short8*)(&sA[(wm + a) * 40 + g * 8]);
    const short8 bf0 = *(const short8*)(&sB[(wn + a) * 40 + g * 8]);
    const short8 bf1 = *(const short8*)(&sB[(wn + 16 + a) * 40 + g * 8]);
    acc0 = __builtin_amdgcn_mfma_f32_16x16x32_bf16(af, bf0, acc0, 0, 0, 0);
    acc1 = __builtin_amdgcn_mfma_f32_16x16x32_bf16(af, bf1, acc1, 0, 0, 0);
    __syncthreads();
  }

  // C fragments -> LDS (row = wm + g*4 + r, col = wn + nt*16 + a)
#pragma unroll
  for (int r = 0; r < 4; ++r) {
    sC[wm + g * 4 + r][wn + a] = acc0[r];
    sC[wm + g * 4 + r][wn + 16 + a] = acc1[r];
  }
  __syncthreads();

  if constexpr (OMODE == 2) {
    // transposed store: out[n][m], thread t covers n = t>>2, m = (t&3)*8..+8
    const int n = tid >> 2, iq = (tid & 3) * 8;
    const float bv = bias ? bias[n] : 0.f;
    ushort8v o;
#pragma unroll
    for (int cc = 0; cc < 8; ++cc) o[cc] = f2bf(sC[iq + cc][n] + bv);
    *(ushort8v*)((unsigned short*)Cp + (size_t)n * ldc + iq) = o;
  } else {
    const int m = tid >> 3, c8 = (tid & 7) * 8;
    float v[8];
#pragma unroll
    for (int cc = 0; cc < 8; ++cc) {
      v[cc] = sC[m][c8 + cc];
      if (bias) v[cc] += bias[c8 + cc];
    }
    if constexpr (OMODE == 1) {
      ushort8v o;
#pragma unroll
      for (int cc = 0; cc < 8; ++cc) o[cc] = f2bf(v[cc]);
      *(ushort8v*)((unsigned short*)Cp + (size_t)m * ldc + c8) = o;
    } else {
      *(float4*)((float*)Cp + (size_t)m * ldc + c8) =
          make_float4(v[0], v[1], v[2], v[3]);
      *(float4*)((float*)Cp + (size_t)m * ldc + c8 + 4) =
          make_float4(v[4], v[5], v[6], v[7]);
    }
  }
}

// valT[b][n][i] = (x @ WvT + bv)^T  : A = x (f32), transposed bf16 store
__global__ __launch_bounds__(256) void gemm_xw_t_kernel(
    const float* __restrict__ x, const unsigned short* __restrict__ WvT,
    const float* __restrict__ bv, unsigned short* __restrict__ valT) {
  const int n0 = blockIdx.x * 64;
  const int m0 = blockIdx.y * 32;  // m = b*512 + i
  const int b = m0 >> 9, i0 = m0 & 511;
  gemm32x64<1, 2>(x + (size_t)m0 * 512, 512, WvT + (size_t)n0 * 512, 512,
                  bv + n0, valT + (size_t)b * 262144 + (size_t)n0 * 512 + i0,
                  512);
}

// ctx[b,i,h*64+d] = sum_j attn[b,h,i,j] * valT[b][h*64+d][j]
__global__ __launch_bounds__(256) void attn_value_kernel(
    const unsigned short* __restrict__ attnb,
    const unsigned short* __restrict__ valT, unsigned short* __restrict__ ctx) {
  const int bid = blockIdx.x;  // it(16) x h(8) x b(4)
  const int it = bid & 15, h = (bid >> 4) & 7, b = bid >> 7;
  const int i0 = it * 32;
  gemm32x64<0, 1>(attnb + ((size_t)((b * 8 + h) * 512 + i0)) * 512, 512,
                  valT + (size_t)b * 262144 + (size_t)(h * 64) * 512, 512,
                  nullptr, ctx + ((size_t)(b * 512 + i0)) * 512 + h * 64, 512);
}

// proj = ctx @ WoT + bo  (f32 out)
__global__ __launch_bounds__(256) void gemm_proj_kernel(
    const unsigned short* __restrict__ ctx, const unsigned short* __restrict__ WoT,
    const float* __restrict__ bo, float* __restrict__ proj) {
  const int n0 = blockIdx.x * 64;
  const int m0 = blockIdx.y * 32;
  gemm32x64<0, 0>(ctx + (size_t)m0 * 512, 512, WoT + (size_t)n0 * 512, 512,
                  bo + n0, proj + (size_t)m0 * 512 + n0, 512);
}

// ---------------------------------------------------------------------------
// Fused pair-MLP + mask + softmax, v6: A-fragments built DIRECTLY from global
// refCov (no LDS staging, no chunk barriers).  Block = (b,i), 4 waves; wave w
// owns rows w*64..w*64+64 of each 256-row chunk.
// ---------------------------------------------------------------------------
__global__ __launch_bounds__(256) void scores_softmax_kernel(
    const float* __restrict__ refCov, const int* __restrict__ mask,
    const float* __restrict__ W1, const float* __restrict__ b1,
    const float* __restrict__ W2, const float* __restrict__ b2,
    unsigned short* __restrict__ attnb) {
  __shared__ unsigned short sH1[256 * 34];  // 17408 B
  __shared__ unsigned short sMask[2 * 256];
  __shared__ float redbuf[4][16];
  __shared__ int s_any;

  const int tid = threadIdx.x;
  const int b = blockIdx.x >> 9;
  const int i = blockIdx.x & (L - 1);
  const int w = tid >> 6;
  const int l = tid & 63;
  const int g = l >> 4;
  const int a = l & 15;

  const int mi = mask[b * L + i];
  const int m0 = mask[b * L + tid];
  const int m1 = mask[b * L + 256 + tid];
  if (tid == 0) s_any = 0;
  __syncthreads();
  if (m0 | m1) s_any = 1;  // benign same-value race
  sMask[tid] = (unsigned short)(m0 != 0);
  sMask[tid + 256] = (unsigned short)(m1 != 0);
  __syncthreads();

  if (mi == 0 || s_any == 0) {
    // fully-masked row: uniform 1/L (= 2^-9, exact in bf16)
    const ushort4 u4 = {0x3B00u, 0x3B00u, 0x3B00u, 0x3B00u};
#pragma unroll
    for (int q = 0; q < 4; ++q) {
      const int f4 = q * 256 + tid;  // 1024 ushort4 = NH*L shorts
      const int h = f4 >> 7;
      const int c4 = f4 & 127;
      *(ushort4*)(attnb + ((size_t)(b * NH + h) * L + i) * L + c4 * 4) = u4;
    }
    return;
  }

  // ---- per-block weight fragments (k = ks*32 + g*8 + e) ----
  short8 w1f[2][2];  // [kstep][ntile]
#pragma unroll
  for (int ks = 0; ks < 2; ++ks)
#pragma unroll
    for (int nt = 0; nt < 2; ++nt)
#pragma unroll
      for (int e = 0; e < 8; ++e) {
        const int k = ks * 32 + g * 8 + e;
        w1f[ks][nt][e] =
            (k < RIN) ? (short)f2bf(W1[k * RHID + nt * 16 + a]) : (short)0;
      }
  short8 w2f;
#pragma unroll
  for (int e = 0; e < 8; ++e) {
    const int k = g * 8 + e;
    w2f[e] = (a < NH) ? (short)f2bf(W2[k * NH + a]) : (short)0;
  }
  const float b1v0 = b1[a];
  const float b1v1 = b1[16 + a];
  const float b2v = (a < NH) ? b2[a] : 0.f;

  f32x4 sc[2][4];
  unsigned vbits[2];

#pragma unroll
  for (int c = 0; c < 2; ++c) {
    // ---- layer 1: h1 = relu(RC @ W1 + b1); A-frags direct from global ----
    f32x4 h1acc[4][2];
#pragma unroll
    for (int mt = 0; mt < 4; ++mt) {
      h1acc[mt][0] = f32x4{b1v0, b1v0, b1v0, b1v0};
      h1acc[mt][1] = f32x4{b1v1, b1v1, b1v1, b1v1};
    }
#pragma unroll
    for (int mt = 0; mt < 4; ++mt) {
      const int j = c * 256 + w * 64 + mt * 16 + a;
      const float* rp = refCov + ((size_t)(b * L + i) * L + j) * RIN;
      short8 af0, af1;
#pragma unroll
      for (int e = 0; e < 8; ++e) af0[e] = (short)f2bf(rp[g * 8 + e]);
#pragma unroll
      for (int e = 0; e < 8; ++e) {
        const int k = 32 + g * 8 + e;
        const float xv = (k < RIN) ? rp[k] : 0.f;
        af1[e] = (short)f2bf(xv);
      }
      h1acc[mt][0] = __builtin_amdgcn_mfma_f32_16x16x32_bf16(
          af0, w1f[0][0], h1acc[mt][0], 0, 0, 0);
      h1acc[mt][1] = __builtin_amdgcn_mfma_f32_16x16x32_bf16(
          af0, w1f[0][1], h1acc[mt][1], 0, 0, 0);
      h1acc[mt][0] = __builtin_amdgcn_mfma_f32_16x16x32_bf16(
          af1, w1f[1][0], h1acc[mt][0], 0, 0, 0);
      h1acc[mt][1] = __builtin_amdgcn_mfma_f32_16x16x32_bf16(
          af1, w1f[1][1], h1acc[mt][1], 0, 0, 0);
    }

    // ---- relu + wave-local transpose of h1 through LDS (no barrier) ----
#pragma unroll
    for (int mt = 0; mt < 4; ++mt)
#pragma unroll
      for (int nt = 0; nt < 2; ++nt)
#pragma unroll
        for (int r = 0; r < 4; ++r) {
          const float v = fmaxf(h1acc[mt][nt][r], 0.f);
          const int row = w * 64 + mt * 16 + g * 4 + r;
          const int col = nt * 16 + a;
          sH1[row * 34 + col] = f2bf(v);
        }

    // ---- layer 2: S = h1 @ W2 + b2, 4 MFMA / wave ----
#pragma unroll
    for (int mt = 0; mt < 4; ++mt) {
      const int row = w * 64 + mt * 16 + a;
      const short8 af2 = *(const short8*)(&sH1[row * 34 + g * 8]);
      f32x4 acc = f32x4{b2v, b2v, b2v, b2v};
      acc = __builtin_amdgcn_mfma_f32_16x16x32_bf16(af2, w2f, acc, 0, 0, 0);
      sc[c][mt] = acc;
    }

    // ---- validity bits ----
    unsigned vb = 0;
#pragma unroll
    for (int mt = 0; mt < 4; ++mt)
#pragma unroll
      for (int r = 0; r < 4; ++r) {
        const int j = c * 256 + w * 64 + mt * 16 + g * 4 + r;
        if (sMask[j]) vb |= 1u << (mt * 4 + r);
      }
    vbits[c] = vb;
  }

  // ---- masked softmax over j for head h = a (lanes a<8 real) ----
  float mx = -INFINITY;
#pragma unroll
  for (int c = 0; c < 2; ++c)
#pragma unroll
    for (int mt = 0; mt < 4; ++mt)
#pragma unroll
      for (int r = 0; r < 4; ++r)
        if ((vbits[c] >> (mt * 4 + r)) & 1u) mx = fmaxf(mx, sc[c][mt][r]);
  mx = fmaxf(mx, __shfl_xor(mx, 16, 64));
  mx = fmaxf(mx, __shfl_xor(mx, 32, 64));
  if (g == 0) redbuf[w][a] = mx;
  __syncthreads();
  const float rmax = fmaxf(fmaxf(redbuf[0][a], redbuf[1][a]),
                           fmaxf(redbuf[2][a], redbuf[3][a]));
  __syncthreads();

  float lsum = 0.f;
#pragma unroll
  for (int c = 0; c < 2; ++c)
#pragma unroll
    for (int mt = 0; mt < 4; ++mt)
#pragma unroll
      for (int r = 0; r < 4; ++r) {
        const int valid = (vbits[c] >> (mt * 4 + r)) & 1u;
        const float e = valid ? __expf(sc[c][mt][r] - rmax) : 0.f;
        sc[c][mt][r] = e;
        lsum += e;
      }
  lsum += __shfl_xor(lsum, 16, 64);
  lsum += __shfl_xor(lsum, 32, 64);
  if (g == 0) redbuf[w][a] = lsum;
  __syncthreads();
  const float rsum = redbuf[0][a] + redbuf[1][a] + redbuf[2][a] + redbuf[3][a];
  const float inv = 1.f / rsum;

  if (a < NH) {
#pragma unroll
    for (int c = 0; c < 2; ++c)
#pragma unroll
      for (int mt = 0; mt < 4; ++mt) {
        ushort4 o;
        o.x = f2bf(sc[c][mt][0] * inv);
        o.y = f2bf(sc[c][mt][1] * inv);
        o.z = f2bf(sc[c][mt][2] * inv);
        o.w = f2bf(sc[c][mt][3] * inv);
        *(ushort4*)(attnb + ((size_t)(b * NH + a) * L + i) * L + c * 256 +
                    w * 64 + mt * 16 + g * 4) = o;
      }
  }
}

// ---------------------------------------------------------------------------
// out = LN(x + proj) * gamma + beta   (block per row)
// ---------------------------------------------------------------------------
__global__ __launch_bounds__(256) void residual_ln_kernel(
    const float* __restrict__ x, const float* __restrict__ proj,
    const float* __restrict__ gamma, const float* __restrict__ beta,
    float* __restrict__ out) {
  const int row = blockIdx.x;
  const int tid = threadIdx.x;
  __shared__ float redS[4], redQ[4];
  float y[2];
  float ls = 0.f, lq = 0.f;
#pragma unroll
  for (int p = 0; p < 2; ++p) {
    const int c = tid + p * 256;
    const float v = x[(size_t)row * H + c] + proj[(size_t)row * H + c];
    y[p] = v;
    ls += v;
    lq += v * v;
  }
  const int lane = tid & 63, wave = tid >> 6;
  ls = waveReduceSum(ls);
  lq = waveReduceSum(lq);
  if (lane == 0) {
    redS[wave] = ls;
    redQ[wave] = lq;
  }
  __syncthreads();
  const float sum = redS[0] + redS[1] + redS[2] + redS[3];
  const float sq = redQ[0] + redQ[1] + redQ[2] + redQ[3];
  const float mu = sum * (1.f / H);
  const float var = sq * (1.f / H) - mu * mu;
  const float inv = rsqrtf(var + 1e-5f);
#pragma unroll
  for (int p = 0; p < 2; ++p) {
    const int c = tid + p * 256;
    out[(size_t)row * H + c] = (y[p] - mu) * inv * gamma[c] + beta[c];
  }
}

extern "C" void kernel_launch(void* const* d_in, const int* in_sizes, int n_in,
                              void* d_out, int out_size, void* d_ws,
                              size_t ws_size, hipStream_t stream) {
  const float* x = (const float*)d_in[0];
  const int* mask = (const int*)d_in[1];
  const float* refCov = (const float*)d_in[2];
  const float* Wv = (const float*)d_in[3];
  const float* bv = (const float*)d_in[4];
  const float* W1 = (const float*)d_in[5];
  const float* b1 = (const float*)d_in[6];
  const float* W2 = (const float*)d_in[7];
  const float* b2 = (const float*)d_in[8];
  const float* Wo = (const float*)d_in[9];
  const float* bo = (const float*)d_in[10];
  const float* gamma = (const float*)d_in[11];
  const float* beta = (const float*)d_in[12];
  float* out = (float*)d_out;

  // workspace layout
  const size_t n_attn = (size_t)B * NH * L * L;  // 8388608 (bf16)
  const size_t n_blh = (size_t)B * L * H;        // 1048576
  const size_t n_w = (size_t)H * H;              // 262144
  unsigned short* attnb = (unsigned short*)d_ws;
  unsigned short* valT = attnb + n_attn;
  unsigned short* ctx = valT + n_blh;
  unsigned short* WvT = ctx + n_blh;
  unsigned short* WoT = WvT + n_w;
  float* proj = (float*)(WoT + n_w);
  const size_t needed = (n_attn + 2 * n_blh + 2 * n_w) * 2 + n_blh * 4;
  if (ws_size < needed) return;

  const int M = B * L;  // 2048

  // 0. W transposes (one launch)
  transpose_w2_kernel<<<dim3(8, 8, 2), 256, 0, stream>>>(Wv, Wo, WvT, WoT);
  // 1. valT = (x @ WvT + bv)^T   (bf16, [b][d][j])
  gemm_xw_t_kernel<<<dim3(8, M / 32), 256, 0, stream>>>(x, WvT, bv, valT);
  // 2. attn = softmax(mask(MLP(refCov)))  (bf16)
  scores_softmax_kernel<<<B * L, 256, 0, stream>>>(refCov, mask, W1, b1, W2,
                                                   b2, attnb);
  // 3. ctx = attn @ value  (bf16)
  attn_value_kernel<<<512, 256, 0, stream>>>(attnb, valT, ctx);
  // 4. proj = ctx @ WoT + bo  (f32)
  gemm_proj_kernel<<<dim3(8, M / 32), 256, 0, stream>>>(ctx, WoT, bo, proj);
  // 5. out = LN(x + proj)
  residual_ln_kernel<<<M, 256, 0, stream>>>(x, proj, gamma, beta, out);
}

// Round 7
// 77.318 us; speedup vs baseline: 7.4460x; 1.0966x over previous
//
#include <hip/hip_runtime.h>
#include <hip/hip_bf16.h>
#include <math.h>

#define B 4
#define L 512
#define H 512
#define NH 8
#define DK 64
#define RIN 53
#define RHID 32

using short8 = __attribute__((ext_vector_type(8))) short;
using ushort8v = __attribute__((ext_vector_type(8))) unsigned short;
using f32x4 = __attribute__((ext_vector_type(4))) float;

__device__ __forceinline__ float waveReduceSum(float v) {
#pragma unroll
  for (int off = 32; off > 0; off >>= 1) v += __shfl_xor(v, off, 64);
  return v;
}

__device__ __forceinline__ unsigned short cvt_bf16(float f) {
  __hip_bfloat16 h = __float2bfloat16(f);  // RNE; compiler packs to cvt_pk
  return __builtin_bit_cast(unsigned short, h);
}

// ---------------------------------------------------------------------------
// per-batch compaction of valid j indices: jidx[b][0..nv-1], nv[b]
// one block of 512 threads per batch
// ---------------------------------------------------------------------------
__global__ __launch_bounds__(512) void compact_mask_kernel(
    const int* __restrict__ mask, int* __restrict__ jidx, int* __restrict__ nv) {
  const int b = blockIdx.x;
  const int tid = threadIdx.x;
  const int lane = tid & 63, wv = tid >> 6;
  __shared__ int wtot[8], woff[8];
  const int m = (mask[b * 512 + tid] != 0);
  const unsigned long long bal = __ballot(m);
  const int lpre = __popcll(bal & ((1ull << lane) - 1ull));
  if (lane == 0) wtot[wv] = __popcll(bal);
  __syncthreads();
  if (tid == 0) {
    int acc = 0;
#pragma unroll
    for (int q = 0; q < 8; ++q) {
      woff[q] = acc;
      acc += wtot[q];
    }
    nv[b] = acc;
  }
  __syncthreads();
  if (m) jidx[b * 512 + woff[wv] + lpre] = tid;
}

// ---------------------------------------------------------------------------
// prep: Wv and Wo [k][n] f32 -> WT[n][k] bf16, one launch, grid (8,8,2)
// ---------------------------------------------------------------------------
__global__ __launch_bounds__(256) void transpose_w2_kernel(
    const float* __restrict__ Wv, const float* __restrict__ Wo,
    unsigned short* __restrict__ WvT, unsigned short* __restrict__ WoT) {
  const float* W = blockIdx.z ? Wo : Wv;
  unsigned short* WT = blockIdx.z ? WoT : WvT;
  __shared__ float sT[64][65];
  const int k0 = blockIdx.x * 64, n0 = blockIdx.y * 64;
  const int tid = threadIdx.x;
  {
    const int r = tid >> 2, c0 = (tid & 3) * 16;
#pragma unroll
    for (int cc = 0; cc < 16; cc += 4) {
      const float4 v =
          *(const float4*)(W + (size_t)(k0 + r) * 512 + n0 + c0 + cc);
      sT[r][c0 + cc] = v.x;
      sT[r][c0 + cc + 1] = v.y;
      sT[r][c0 + cc + 2] = v.z;
      sT[r][c0 + cc + 3] = v.w;
    }
  }
  __syncthreads();
  {
    const int n = tid >> 2, c0 = (tid & 3) * 16;
    ushort8v o0, o1;
#pragma unroll
    for (int cc = 0; cc < 8; ++cc) o0[cc] = cvt_bf16(sT[c0 + cc][n]);
#pragma unroll
    for (int cc = 0; cc < 8; ++cc) o1[cc] = cvt_bf16(sT[c0 + 8 + cc][n]);
    *(ushort8v*)(WT + (size_t)(n0 + n) * 512 + k0 + c0) = o0;
    *(ushort8v*)(WT + (size_t)(n0 + n) * 512 + k0 + c0 + 8) = o1;
  }
}

// ---------------------------------------------------------------------------
// bf16 MFMA GEMM core: C[32 m x 64 n], K=512, 256 thr (4 waves, 2x2 quads).
// A: [m][k] bf16 (AMODE 0) or f32 converted on stage (AMODE 1).
// B: [n][k] bf16 (pre-transposed), coalesced ushort8 loads.
// OMODE: 0 = f32 store, 1 = bf16 store, 2 = bf16 TRANSPOSED store (C^T).
// ---------------------------------------------------------------------------
template <int AMODE, int OMODE>
__device__ __forceinline__ void gemm32x64(
    const void* __restrict__ Aq, int lda, const unsigned short* __restrict__ Bs,
    int ldb, const float* __restrict__ bias, void* __restrict__ Cp, int ldc) {
  __shared__ unsigned short sA[32 * 40];
  __shared__ unsigned short sB[64 * 40];
  __shared__ float sC[32][68];
  const int tid = threadIdx.x;
  const int w = tid >> 6, l = tid & 63, g = l >> 4, a = l & 15;
  const int wm = (w >> 1) * 16, wn = (w & 1) * 32;
  f32x4 acc0 = {}, acc1 = {};
  ushort8v aReg{}, bReg;

  auto loadA = [&](int k0) {
    ushort8v r{};
    if (tid < 128) {
      if constexpr (AMODE == 1) {
        const float* Af = (const float*)Aq;
        const float* p = Af + (size_t)(tid >> 2) * lda + k0 + (tid & 3) * 8;
        const float4 v0 = *(const float4*)p;
        const float4 v1 = *(const float4*)(p + 4);
        r[0] = cvt_bf16(v0.x); r[1] = cvt_bf16(v0.y);
        r[2] = cvt_bf16(v0.z); r[3] = cvt_bf16(v0.w);
        r[4] = cvt_bf16(v1.x); r[5] = cvt_bf16(v1.y);
        r[6] = cvt_bf16(v1.z); r[7] = cvt_bf16(v1.w);
      } else {
        const unsigned short* Ab = (const unsigned short*)Aq;
        r = *(const ushort8v*)(Ab + (size_t)(tid >> 2) * lda + k0 + (tid & 3) * 8);
      }
    }
    return r;
  };
  auto loadB = [&](int k0) {
    return *(const ushort8v*)(Bs + (size_t)(tid >> 2) * ldb + k0 + (tid & 3) * 8);
  };

  aReg = loadA(0);
  bReg = loadB(0);
  for (int k0 = 0; k0 < 512; k0 += 32) {
    if (tid < 128) *(ushort8v*)(&sA[(tid >> 2) * 40 + (tid & 3) * 8]) = aReg;
    *(ushort8v*)(&sB[(tid >> 2) * 40 + (tid & 3) * 8]) = bReg;
    __syncthreads();
    if (k0 < 480) {
      aReg = loadA(k0 + 32);
      bReg = loadB(k0 + 32);
    }
    const short8 af = *(const short8*)(&sA[(wm + a) * 40 + g * 8]);
    const short8 bf0 = *(const short8*)(&sB[(wn + a) * 40 + g * 8]);
    const short8 bf1 = *(const short8*)(&sB[(wn + 16 + a) * 40 + g * 8]);
    acc0 = __builtin_amdgcn_mfma_f32_16x16x32_bf16(af, bf0, acc0, 0, 0, 0);
    acc1 = __builtin_amdgcn_mfma_f32_16x16x32_bf16(af, bf1, acc1, 0, 0, 0);
    __syncthreads();
  }

  // C fragments -> LDS (row = wm + g*4 + r, col = wn + nt*16 + a)
#pragma unroll
  for (int r = 0; r < 4; ++r) {
    sC[wm + g * 4 + r][wn + a] = acc0[r];
    sC[wm + g * 4 + r][wn + 16 + a] = acc1[r];
  }
  __syncthreads();

  if constexpr (OMODE == 2) {
    // transposed store: out[n][m], thread t covers n = t>>2, m = (t&3)*8..+8
    const int n = tid >> 2, iq = (tid & 3) * 8;
    const float bv = bias ? bias[n] : 0.f;
    ushort8v o;
#pragma unroll
    for (int cc = 0; cc < 8; ++cc) o[cc] = cvt_bf16(sC[iq + cc][n] + bv);
    *(ushort8v*)((unsigned short*)Cp + (size_t)n * ldc + iq) = o;
  } else {
    const int m = tid >> 3, c8 = (tid & 7) * 8;
    float v[8];
#pragma unroll
    for (int cc = 0; cc < 8; ++cc) {
      v[cc] = sC[m][c8 + cc];
      if (bias) v[cc] += bias[c8 + cc];
    }
    if constexpr (OMODE == 1) {
      ushort8v o;
#pragma unroll
      for (int cc = 0; cc < 8; ++cc) o[cc] = cvt_bf16(v[cc]);
      *(ushort8v*)((unsigned short*)Cp + (size_t)m * ldc + c8) = o;
    } else {
      *(float4*)((float*)Cp + (size_t)m * ldc + c8) =
          make_float4(v[0], v[1], v[2], v[3]);
      *(float4*)((float*)Cp + (size_t)m * ldc + c8 + 4) =
          make_float4(v[4], v[5], v[6], v[7]);
    }
  }
}

// valT[b][n][i] = (x @ WvT + bv)^T  : A = x (f32), transposed bf16 store
__global__ __launch_bounds__(256) void gemm_xw_t_kernel(
    const float* __restrict__ x, const unsigned short* __restrict__ WvT,
    const float* __restrict__ bv, unsigned short* __restrict__ valT) {
  const int n0 = blockIdx.x * 64;
  const int m0 = blockIdx.y * 32;  // m = b*512 + i
  const int b = m0 >> 9, i0 = m0 & 511;
  gemm32x64<1, 2>(x + (size_t)m0 * 512, 512, WvT + (size_t)n0 * 512, 512,
                  bv + n0, valT + (size_t)b * 262144 + (size_t)n0 * 512 + i0,
                  512);
}

// ctx[b,i,h*64+d] = sum_j attn[b,h,i,j] * valT[b][h*64+d][j]
__global__ __launch_bounds__(256) void attn_value_kernel(
    const unsigned short* __restrict__ attnb,
    const unsigned short* __restrict__ valT, unsigned short* __restrict__ ctx) {
  const int bid = blockIdx.x;  // it(16) x h(8) x b(4)
  const int it = bid & 15, h = (bid >> 4) & 7, b = bid >> 7;
  const int i0 = it * 32;
  gemm32x64<0, 1>(attnb + ((size_t)((b * 8 + h) * 512 + i0)) * 512, 512,
                  valT + (size_t)b * 262144 + (size_t)(h * 64) * 512, 512,
                  nullptr, ctx + ((size_t)(b * 512 + i0)) * 512 + h * 64, 512);
}

// proj = ctx @ WoT + bo  (f32 out)
__global__ __launch_bounds__(256) void gemm_proj_kernel(
    const unsigned short* __restrict__ ctx, const unsigned short* __restrict__ WoT,
    const float* __restrict__ bo, float* __restrict__ proj) {
  const int n0 = blockIdx.x * 64;
  const int m0 = blockIdx.y * 32;
  gemm32x64<0, 0>(ctx + (size_t)m0 * 512, 512, WoT + (size_t)n0 * 512, 512,
                  bo + n0, proj + (size_t)m0 * 512 + n0, 512);
}

// ---------------------------------------------------------------------------
// Fused pair-MLP + mask + softmax, v7: compacted valid-j tiles.
// Block = (b,i); 4 waves; wave w handles tiles t = w, w+4, ..., t < NT where
// NT = ceil(nv/16).  A-fragments direct from global refCov rows jidx[s].
// Output: zero-fill the 8x512 slab, then scatter softmax values to valid j.
// ---------------------------------------------------------------------------
__global__ __launch_bounds__(256) void scores_softmax_kernel(
    const float* __restrict__ refCov, const int* __restrict__ mask,
    const int* __restrict__ jidx, const int* __restrict__ nvArr,
    const float* __restrict__ W1, const float* __restrict__ b1,
    const float* __restrict__ W2, const float* __restrict__ b2,
    unsigned short* __restrict__ attnb) {
  __shared__ unsigned short sH1[512 * 34];  // 34816 B
  __shared__ int sJ[512];
  __shared__ float redbuf[4][16];

  const int tid = threadIdx.x;
  const int b = blockIdx.x >> 9;
  const int i = blockIdx.x & (L - 1);
  const int w = tid >> 6;
  const int l = tid & 63;
  const int g = l >> 4;
  const int a = l & 15;

  const int mi = mask[b * L + i];
  const int nv = nvArr[b];

  if (mi == 0 || nv == 0) {
    // fully-masked row: uniform 1/L (= 2^-9, exact in bf16)
    const ushort4 u4 = {0x3B00u, 0x3B00u, 0x3B00u, 0x3B00u};
#pragma unroll
    for (int q = 0; q < 4; ++q) {
      const int f4 = q * 256 + tid;  // 1024 ushort4 = NH*L shorts
      const int h = f4 >> 7;
      const int c4 = f4 & 127;
      *(ushort4*)(attnb + ((size_t)(b * NH + h) * L + i) * L + c4 * 4) = u4;
    }
    return;
  }

  // zero-fill the output slab (8 heads x 512); scatter overwrites valid j later
  {
    const ushort8v z{};
#pragma unroll
    for (int q = 0; q < 2; ++q) {
      const int idx = q * 256 + tid;  // 512 ushort8 = 8*512 shorts
      const int h = idx >> 6;
      const int c8 = idx & 63;
      *(ushort8v*)(attnb + ((size_t)(b * NH + h) * L + i) * L + c8 * 8) = z;
    }
  }
  // stage jidx for this batch
  sJ[tid] = jidx[b * 512 + tid];
  sJ[tid + 256] = jidx[b * 512 + 256 + tid];

  // ---- per-block weight fragments (k = ks*32 + g*8 + e) ----
  short8 w1f[2][2];  // [kstep][ntile]
#pragma unroll
  for (int ks = 0; ks < 2; ++ks)
#pragma unroll
    for (int nt = 0; nt < 2; ++nt)
#pragma unroll
      for (int e = 0; e < 8; ++e) {
        const int k = ks * 32 + g * 8 + e;
        w1f[ks][nt][e] =
            (k < RIN) ? (short)cvt_bf16(W1[k * RHID + nt * 16 + a]) : (short)0;
      }
  short8 w2f;
#pragma unroll
  for (int e = 0; e < 8; ++e) {
    const int k = g * 8 + e;
    w2f[e] = (a < NH) ? (short)cvt_bf16(W2[k * NH + a]) : (short)0;
  }
  const float b1v0 = b1[a];
  const float b1v1 = b1[16 + a];
  const float b2v = (a < NH) ? b2[a] : 0.f;

  __syncthreads();  // sJ ready

  const int NT = (nv + 15) >> 4;  // <= 32
  f32x4 sc[8];

#pragma unroll
  for (int mt = 0; mt < 8; ++mt) {
    const int t = mt * 4 + w;
    if (t >= NT) continue;
    // ---- A row: j = jidx[min(t*16+a, nv-1)] ----
    const int s = t * 16 + a;
    const int j = sJ[(s < nv) ? s : (nv - 1)];
    const float* rp = refCov + ((size_t)((b << 9) + i) * 512 + j) * RIN;

    // af0: k = g*8 + e  (0..31, all in-row)
    const float4 u0 = *(const float4*)(rp + g * 8);
    const float4 u1 = *(const float4*)(rp + g * 8 + 4);
    // af1: k = 32 + g*8 + e, clamped in-row loads + selects (no OOB ever)
    const int base0 = (g < 3) ? (32 + g * 8) : 32;
    const int base1 = (g == 0) ? 36 : (g == 1) ? 44 : 49;  // g>=2 -> 49
    const float4 v0 = *(const float4*)(rp + base0);
    const float4 v1 = *(const float4*)(rp + base1);
    float t1[8];
    if (g < 3) {
      t1[0] = v0.x; t1[1] = v0.y; t1[2] = v0.z; t1[3] = v0.w;
    } else {
      t1[0] = 0.f; t1[1] = 0.f; t1[2] = 0.f; t1[3] = 0.f;
    }
    if (g < 2) {
      t1[4] = v1.x; t1[5] = v1.y; t1[6] = v1.z; t1[7] = v1.w;
    } else if (g == 2) {
      t1[4] = v1.w;  // k = 52
      t1[5] = 0.f; t1[6] = 0.f; t1[7] = 0.f;
    } else {
      t1[4] = 0.f; t1[5] = 0.f; t1[6] = 0.f; t1[7] = 0.f;
    }
    short8 af0, af1;
    af0[0] = (short)cvt_bf16(u0.x); af0[1] = (short)cvt_bf16(u0.y);
    af0[2] = (short)cvt_bf16(u0.z); af0[3] = (short)cvt_bf16(u0.w);
    af0[4] = (short)cvt_bf16(u1.x); af0[5] = (short)cvt_bf16(u1.y);
    af0[6] = (short)cvt_bf16(u1.z); af0[7] = (short)cvt_bf16(u1.w);
#pragma unroll
    for (int e = 0; e < 8; ++e) af1[e] = (short)cvt_bf16(t1[e]);

    // ---- layer 1: h1 = relu(RC @ W1 + b1), 4 MFMA ----
    f32x4 h0 = f32x4{b1v0, b1v0, b1v0, b1v0};
    f32x4 h1v = f32x4{b1v1, b1v1, b1v1, b1v1};
    h0 = __builtin_amdgcn_mfma_f32_16x16x32_bf16(af0, w1f[0][0], h0, 0, 0, 0);
    h1v = __builtin_amdgcn_mfma_f32_16x16x32_bf16(af0, w1f[0][1], h1v, 0, 0, 0);
    h0 = __builtin_amdgcn_mfma_f32_16x16x32_bf16(af1, w1f[1][0], h0, 0, 0, 0);
    h1v = __builtin_amdgcn_mfma_f32_16x16x32_bf16(af1, w1f[1][1], h1v, 0, 0, 0);

    // ---- relu + wave-local transpose through LDS ----
#pragma unroll
    for (int r = 0; r < 4; ++r) {
      sH1[(t * 16 + g * 4 + r) * 34 + a] = cvt_bf16(fmaxf(h0[r], 0.f));
      sH1[(t * 16 + g * 4 + r) * 34 + 16 + a] = cvt_bf16(fmaxf(h1v[r], 0.f));
    }

    // ---- layer 2: S = h1 @ W2 + b2, 1 MFMA ----
    const short8 af2 = *(const short8*)(&sH1[(t * 16 + a) * 34 + g * 8]);
    f32x4 acc = f32x4{b2v, b2v, b2v, b2v};
    sc[mt] = __builtin_amdgcn_mfma_f32_16x16x32_bf16(af2, w2f, acc, 0, 0, 0);
  }

  // ---- masked softmax over valid slots for head h = a (a < 8 real) ----
  float mx = -INFINITY;
#pragma unroll
  for (int mt = 0; mt < 8; ++mt) {
    const int t = mt * 4 + w;
    if (t >= NT) continue;
#pragma unroll
    for (int r = 0; r < 4; ++r) {
      const int s = t * 16 + g * 4 + r;
      if (s < nv) mx = fmaxf(mx, sc[mt][r]);
    }
  }
  mx = fmaxf(mx, __shfl_xor(mx, 16, 64));
  mx = fmaxf(mx, __shfl_xor(mx, 32, 64));
  if (g == 0) redbuf[w][a] = mx;
  __syncthreads();
  const float rmax = fmaxf(fmaxf(redbuf[0][a], redbuf[1][a]),
                           fmaxf(redbuf[2][a], redbuf[3][a]));
  __syncthreads();

  float lsum = 0.f;
#pragma unroll
  for (int mt = 0; mt < 8; ++mt) {
    const int t = mt * 4 + w;
    if (t >= NT) continue;
#pragma unroll
    for (int r = 0; r < 4; ++r) {
      const int s = t * 16 + g * 4 + r;
      const float e = (s < nv) ? __expf(sc[mt][r] - rmax) : 0.f;
      sc[mt][r] = e;
      lsum += e;
    }
  }
  lsum += __shfl_xor(lsum, 16, 64);
  lsum += __shfl_xor(lsum, 32, 64);
  if (g == 0) redbuf[w][a] = lsum;
  __syncthreads();
  const float rsum = redbuf[0][a] + redbuf[1][a] + redbuf[2][a] + redbuf[3][a];
  const float inv = 1.f / rsum;

  // ---- scatter to attn (zero-filled above; >=2 barriers since) ----
  if (a < NH) {
    unsigned short* dst = attnb + ((size_t)(b * NH + a) * L + i) * L;
#pragma unroll
    for (int mt = 0; mt < 8; ++mt) {
      const int t = mt * 4 + w;
      if (t >= NT) continue;
#pragma unroll
      for (int r = 0; r < 4; ++r) {
        const int s = t * 16 + g * 4 + r;
        if (s < nv) dst[sJ[s]] = cvt_bf16(sc[mt][r] * inv);
      }
    }
  }
}

// ---------------------------------------------------------------------------
// out = LN(x + proj) * gamma + beta   (block per row)
// ---------------------------------------------------------------------------
__global__ __launch_bounds__(256) void residual_ln_kernel(
    const float* __restrict__ x, const float* __restrict__ proj,
    const float* __restrict__ gamma, const float* __restrict__ beta,
    float* __restrict__ out) {
  const int row = blockIdx.x;
  const int tid = threadIdx.x;
  __shared__ float redS[4], redQ[4];
  float y[2];
  float ls = 0.f, lq = 0.f;
#pragma unroll
  for (int p = 0; p < 2; ++p) {
    const int c = tid + p * 256;
    const float v = x[(size_t)row * H + c] + proj[(size_t)row * H + c];
    y[p] = v;
    ls += v;
    lq += v * v;
  }
  const int lane = tid & 63, wave = tid >> 6;
  ls = waveReduceSum(ls);
  lq = waveReduceSum(lq);
  if (lane == 0) {
    redS[wave] = ls;
    redQ[wave] = lq;
  }
  __syncthreads();
  const float sum = redS[0] + redS[1] + redS[2] + redS[3];
  const float sq = redQ[0] + redQ[1] + redQ[2] + redQ[3];
  const float mu = sum * (1.f / H);
  const float var = sq * (1.f / H) - mu * mu;
  const float inv = rsqrtf(var + 1e-5f);
#pragma unroll
  for (int p = 0; p < 2; ++p) {
    const int c = tid + p * 256;
    out[(size_t)row * H + c] = (y[p] - mu) * inv * gamma[c] + beta[c];
  }
}

extern "C" void kernel_launch(void* const* d_in, const int* in_sizes, int n_in,
                              void* d_out, int out_size, void* d_ws,
                              size_t ws_size, hipStream_t stream) {
  const float* x = (const float*)d_in[0];
  const int* mask = (const int*)d_in[1];
  const float* refCov = (const float*)d_in[2];
  const float* Wv = (const float*)d_in[3];
  const float* bv = (const float*)d_in[4];
  const float* W1 = (const float*)d_in[5];
  const float* b1 = (const float*)d_in[6];
  const float* W2 = (const float*)d_in[7];
  const float* b2 = (const float*)d_in[8];
  const float* Wo = (const float*)d_in[9];
  const float* bo = (const float*)d_in[10];
  const float* gamma = (const float*)d_in[11];
  const float* beta = (const float*)d_in[12];
  float* out = (float*)d_out;

  // workspace layout
  const size_t n_attn = (size_t)B * NH * L * L;  // 8388608 (bf16)
  const size_t n_blh = (size_t)B * L * H;        // 1048576
  const size_t n_w = (size_t)H * H;              // 262144
  unsigned short* attnb = (unsigned short*)d_ws;
  unsigned short* valT = attnb + n_attn;
  unsigned short* ctx = valT + n_blh;
  unsigned short* WvT = ctx + n_blh;
  unsigned short* WoT = WvT + n_w;
  float* proj = (float*)(WoT + n_w);
  int* jidx = (int*)(proj + n_blh);
  int* nv = jidx + B * L;
  const size_t needed =
      (n_attn + 2 * n_blh + 2 * n_w) * 2 + n_blh * 4 + (B * L + B) * 4;
  if (ws_size < needed) return;

  const int M = B * L;  // 2048

  // 0a. valid-j compaction per batch
  compact_mask_kernel<<<B, 512, 0, stream>>>(mask, jidx, nv);
  // 0b. W transposes (one launch)
  transpose_w2_kernel<<<dim3(8, 8, 2), 256, 0, stream>>>(Wv, Wo, WvT, WoT);
  // 1. valT = (x @ WvT + bv)^T   (bf16, [b][d][j])
  gemm_xw_t_kernel<<<dim3(8, M / 32), 256, 0, stream>>>(x, WvT, bv, valT);
  // 2. attn = softmax(mask(MLP(refCov)))  (bf16, compacted tiles + scatter)
  scores_softmax_kernel<<<B * L, 256, 0, stream>>>(refCov, mask, jidx, nv, W1,
                                                   b1, W2, b2, attnb);
  // 3. ctx = attn @ value  (bf16)
  attn_value_kernel<<<512, 256, 0, stream>>>(attnb, valT, ctx);
  // 4. proj = ctx @ WoT + bo  (f32)
  gemm_proj_kernel<<<dim3(8, M / 32), 256, 0, stream>>>(ctx, WoT, bo, proj);
  // 5. out = LN(x + proj)
  residual_ln_kernel<<<M, 256, 0, stream>>>(x, proj, gamma, beta, out);
}